// Round 12
// baseline (418.842 us; speedup 1.0000x reference)
//
#include <hip/hip_runtime.h>

#define NX 256
#define NU 128
#define NY 128
#define BSZ 128
#define TT 2048
#define LCH 32
#define KCH 64

typedef _Float16 h8 __attribute__((ext_vector_type(8)));
typedef _Float16 h4 __attribute__((ext_vector_type(4)));
typedef float f4 __attribute__((ext_vector_type(4)));

__device__ __forceinline__ f4 mfma16(h8 a, h8 b, f4 c) {
  return __builtin_amdgcn_mfma_f32_16x16x32_f16(a, b, c, 0, 0, 0);
}
#define PIN(x) asm volatile("" : "+v"(x))
#define LBAR() asm volatile("s_waitcnt lgkmcnt(0)\n\ts_barrier" ::: "memory")

__device__ __forceinline__ int swz256(int row, int bc) { return row * 256 + (bc ^ ((row & 7) << 4)); }

__device__ __forceinline__ h8 cvt8(f4 lo, f4 hi) {
  h8 h;
#pragma unroll
  for (int j = 0; j < 4; ++j) { h[j] = (_Float16)lo[j]; h[j + 4] = (_Float16)hi[j]; }
  return h;
}
__device__ __forceinline__ h4 h4cvt(f4 v) {
  h4 h;
#pragma unroll
  for (int j = 0; j < 4; ++j) h[j] = (_Float16)v[j];
  return h;
}

// ---- fp32 GEMM core: 32x32 tile, K=256, lda=256, dbuf K=64 rounds + reg prefetch ----
__device__ __forceinline__ void mm_core(const float* __restrict__ a, const float* __restrict__ b,
                                        int Nb, int i0, int j0, int tid,
                                        float (*As)[32][65], float (*Bs)[64][33],
                                        float acc[2][2]) {
  const int ar = tid >> 4, ac = (tid & 15) * 4;
  const int br = tid >> 3, bc = (tid & 7) * 4;
  const int tx = tid & 15, ty = tid >> 4;
  f4 pa0 = *(const f4*)(a + (size_t)(i0 + ar) * 256 + ac);
  f4 pa1 = *(const f4*)(a + (size_t)(i0 + ar + 16) * 256 + ac);
  f4 pb0 = *(const f4*)(b + (size_t)br * Nb + j0 + bc);
  f4 pb1 = *(const f4*)(b + (size_t)(br + 32) * Nb + j0 + bc);
  for (int r4 = 0; r4 < 4; ++r4) {
    const int bs = r4 & 1;
#pragma unroll
    for (int m = 0; m < 4; ++m) {
      As[bs][ar][ac + m] = pa0[m];
      As[bs][ar + 16][ac + m] = pa1[m];
      Bs[bs][br][bc + m] = pb0[m];
      Bs[bs][br + 32][bc + m] = pb1[m];
    }
    if (r4 < 3) {
      int kk = (r4 + 1) * 64;
      pa0 = *(const f4*)(a + (size_t)(i0 + ar) * 256 + kk + ac);
      pa1 = *(const f4*)(a + (size_t)(i0 + ar + 16) * 256 + kk + ac);
      pb0 = *(const f4*)(b + (size_t)(kk + br) * Nb + j0 + bc);
      pb1 = *(const f4*)(b + (size_t)(kk + br + 32) * Nb + j0 + bc);
    }
    __syncthreads();
#pragma unroll 8
    for (int k = 0; k < 64; ++k) {
      float a0 = As[bs][ty * 2][k], a1 = As[bs][ty * 2 + 1][k];
      float b0 = Bs[bs][k][tx * 2], b1 = Bs[bs][k][tx * 2 + 1];
      acc[0][0] += a0 * b0; acc[0][1] += a0 * b1;
      acc[1][0] += a1 * b0; acc[1][1] += a1 * b1;
    }
  }
}

// ---------------- E,F from M; y0 exact fp32; B16 + G0 seed ----------------
__global__ __launch_bounds__(256) void k_ef(const float* __restrict__ M, const float* __restrict__ B,
                                            const float* __restrict__ C, const float* __restrict__ D,
                                            const float* __restrict__ x0, const float* __restrict__ u,
                                            float* __restrict__ E, float* __restrict__ F,
                                            _Float16* __restrict__ B16, float* __restrict__ out,
                                            float* __restrict__ Gs32, _Float16* __restrict__ Gs16) {
  const int tid = threadIdx.x;
  int z = blockIdx.x >> 6;
  if (z >= 2) {
    if (blockIdx.x < 192) {  // y0
      int idx = (blockIdx.x - 128) * 256 + tid;
      int b = idx >> 7, col = idx & 127;
      const float* crow = C + (size_t)col * 256;
      const float* drow = D + (size_t)col * 128;
      const float* ur = u + (size_t)b * (TT * NU);
      float s = 0.f;
#pragma unroll 8
      for (int j = 0; j < 256; j += 4) {
        f4 cv = *(const f4*)(crow + j);
        f4 xv = *(const f4*)(x0 + j);
        s += cv[0] * xv[0] + cv[1] * xv[1] + cv[2] * xv[2] + cv[3] * xv[3];
      }
#pragma unroll 8
      for (int j = 0; j < 128; j += 4) {
        f4 dv = *(const f4*)(drow + j);
        f4 uv = *(const f4*)(ur + j);
        s += dv[0] * uv[0] + dv[1] * uv[1] + dv[2] * uv[2] + dv[3] * uv[3];
      }
      out[(size_t)b * (TT * NY) + col] = s;
    } else {  // B16 cast + G-stack slot 0 seed (G0 = B)
      int i = (blockIdx.x - 192) * 1024 + tid;
#pragma unroll
      for (int s = 0; s < 4; ++s) {
        int ii = i + s * 256;
        float v = B[ii];
        B16[ii] = (_Float16)v;
        Gs32[ii] = v;
        Gs16[ii] = (_Float16)v;
      }
    }
    return;
  }
  __shared__ float Ps[2][32][65], Qs[2][32][65];
  int tile = blockIdx.x & 63;
  int i0 = (tile >> 3) * 32, j0 = (tile & 7) * 32;
  const int ar = tid >> 4, ac = (tid & 15) * 4;
  const int tx = tid & 15, ty = tid >> 4;
  float acc[2][2] = {{0.f, 0.f}, {0.f, 0.f}};
  int np = (z == 0) ? 2 : 1;
  int rc = 0;
  for (int p = 0; p < np; ++p) {
    int po = (z == 0) ? p * 256 : 256;
    int qo = (z == 0) ? p * 256 : 0;
    f4 p0 = *(const f4*)(M + (size_t)(i0 + po + ar) * 512 + ac);
    f4 p1 = *(const f4*)(M + (size_t)(i0 + po + ar + 16) * 512 + ac);
    f4 q0 = *(const f4*)(M + (size_t)(j0 + qo + ar) * 512 + ac);
    f4 q1 = *(const f4*)(M + (size_t)(j0 + qo + ar + 16) * 512 + ac);
    for (int kk = 0; kk < 512; kk += 64) {
      const int bs = rc & 1;
      ++rc;
#pragma unroll
      for (int m = 0; m < 4; ++m) {
        Ps[bs][ar][ac + m] = p0[m];
        Ps[bs][ar + 16][ac + m] = p1[m];
        Qs[bs][ar][ac + m] = q0[m];
        Qs[bs][ar + 16][ac + m] = q1[m];
      }
      if (kk < 448) {
        int k2 = kk + 64;
        p0 = *(const f4*)(M + (size_t)(i0 + po + ar) * 512 + k2 + ac);
        p1 = *(const f4*)(M + (size_t)(i0 + po + ar + 16) * 512 + k2 + ac);
        q0 = *(const f4*)(M + (size_t)(j0 + qo + ar) * 512 + k2 + ac);
        q1 = *(const f4*)(M + (size_t)(j0 + qo + ar + 16) * 512 + k2 + ac);
      }
      __syncthreads();
#pragma unroll 8
      for (int k = 0; k < 64; ++k) {
        float a0 = Ps[bs][ty * 2][k], a1 = Ps[bs][ty * 2 + 1][k];
        float b0 = Qs[bs][tx * 2][k], b1 = Qs[bs][tx * 2 + 1][k];
        acc[0][0] += a0 * b0; acc[0][1] += a0 * b1;
        acc[1][0] += a1 * b0; acc[1][1] += a1 * b1;
      }
    }
  }
#pragma unroll
  for (int ii = 0; ii < 2; ++ii)
#pragma unroll
    for (int jj = 0; jj < 2; ++jj) {
      int i = i0 + ty * 2 + ii, j = j0 + tx * 2 + jj;
      if (z == 0) {
        float v = 0.5f * acc[ii][jj];
        if (i == j) v += 1e-9f;
        E[i * 256 + j] = v;
      } else {
        F[i * 256 + j] = acc[ii][jj];
      }
    }
}

// ---------------- NS init ----------------
__global__ __launch_bounds__(256) void k_ns0(const float* __restrict__ E,
                                             float* __restrict__ X, float* __restrict__ Y) {
  __shared__ float As[2][32][65];
  __shared__ float Bs[2][64][33];
  __shared__ float s1[256], red[256];
  const int tid = threadIdx.x;
  {
    float s = 0.f;
    const float* row = E + (size_t)tid * 256;
#pragma unroll 8
    for (int j = 0; j < 256; j += 4) {
      f4 e = *(const f4*)(row + j);
      s += e[0] + e[1] + e[2] + e[3];
    }
    s1[tid] = s; red[tid] = s * s;
  }
  __syncthreads();
  for (int o = 128; o > 0; o >>= 1) { if (tid < o) red[tid] += red[tid + o]; __syncthreads(); }
  float n1 = red[0];
  __syncthreads();
  {
    float s = 0.f;
    const float* row = E + (size_t)tid * 256;
#pragma unroll 8
    for (int j = 0; j < 256; j += 4) {
      f4 e = *(const f4*)(row + j);
      f4 vv = *(const f4*)(&s1[j]);
      s += e[0] * vv[0] + e[1] * vv[1] + e[2] * vv[2] + e[3] * vv[3];
    }
    red[tid] = s * s;
  }
  __syncthreads();
  for (int o = 128; o > 0; o >>= 1) { if (tid < o) red[tid] += red[tid + o]; __syncthreads(); }
  float c = sqrtf(n1 / red[0]);
  __syncthreads();
  if (blockIdx.x < 64) {
    int i0 = (blockIdx.x >> 3) * 32, j0 = (blockIdx.x & 7) * 32;
    float acc[2][2] = {{0.f, 0.f}, {0.f, 0.f}};
    mm_core(E, E, 256, i0, j0, tid, As, Bs, acc);
    int tx = tid & 15, ty = tid >> 4;
#pragma unroll
    for (int ii = 0; ii < 2; ++ii)
#pragma unroll
      for (int jj = 0; jj < 2; ++jj) {
        int i = i0 + ty * 2 + ii, j = j0 + tx * 2 + jj;
        Y[(size_t)i * 256 + j] = 2.f * c * E[(size_t)i * 256 + j] - c * c * acc[ii][jj];
      }
  } else {
    int idx = (blockIdx.x - 64) * 1024 + tid * 4;
    int i = idx >> 8, j = idx & 255;
    f4 e = *(const f4*)(E + idx);
    f4 v;
#pragma unroll
    for (int m = 0; m < 4; ++m) v[m] = ((j + m) == i ? 2.f * c : 0.f) - c * c * e[m];
    *(f4*)(X + idx) = v;
  }
}

// ---------------- multi-job fp32 GEMM (up to 4 jobs, nmat batching for G-stack) ----------------
struct MMJob {
  const float* a; const float* b; const float* add;
  float* d32; _Float16* d16;
  int M, N, mode, blk0, nmat;
};

__global__ __launch_bounds__(256) void k_mm(MMJob j0, MMJob j1, MMJob j2, MMJob j3, int njobs) {
  __shared__ float As[2][32][65];
  __shared__ float Bs[2][64][33];
  const int tid = threadIdx.x;
  int bid = blockIdx.x;
  MMJob jb = j0;
  if (njobs > 1 && bid >= j1.blk0) jb = j1;
  if (njobs > 2 && bid >= j2.blk0) jb = j2;
  if (njobs > 3 && bid >= j3.blk0) jb = j3;
  int rel = bid - jb.blk0;
  if (jb.nmat > 1) {  // batched: dst_k = a * b_k, matrices of 256 x N, stride 32768
    int tpm = 8 * (jb.N >> 5);
    int km = rel / tpm;
    rel -= km * tpm;
    jb.b += (size_t)km * 32768;
    if (jb.d32) jb.d32 += (size_t)km * 32768;
    if (jb.d16) jb.d16 += (size_t)km * 32768;
  }
  int ntile = jb.N >> 5;
  int i0 = (rel / ntile) * 32, j0g = (rel % ntile) * 32;
  float acc[2][2] = {{0.f, 0.f}, {0.f, 0.f}};
  mm_core(jb.a, jb.b, jb.N, i0, j0g, tid, As, Bs, acc);
  int tx = tid & 15, ty = tid >> 4;
#pragma unroll
  for (int ii = 0; ii < 2; ++ii)
#pragma unroll
    for (int jj = 0; jj < 2; ++jj) {
      int i = i0 + ty * 2 + ii, j = j0g + tx * 2 + jj;
      size_t o = (size_t)i * jb.N + j;
      float v = acc[ii][jj];
      if (jb.mode == 1) v = 2.f * jb.a[(size_t)i * 256 + j] - v;
      else if (jb.add) v += jb.add[o];
      if (jb.d32) jb.d32[o] = v;
      if (jb.d16) jb.d16[o] = (_Float16)v;
    }
}

// ---------------- phase W replacement: w = sum_i G_{31-i} u(t0+i)  (dense, no recurrence) ----------------
__global__ __launch_bounds__(512, 4) void k_gw(const float* __restrict__ u,
                                               const _Float16* __restrict__ Gs16,
                                               float* __restrict__ w) {
  __shared__ __align__(16) char ub[8192];  // 2 x [16 batch][128 nu] h16
  const int tid = threadIdx.x, lane = tid & 63, wv = tid >> 6;
  const int g = lane >> 4, lr = lane & 15;
  const int chunk = blockIdx.x >> 3, btile = blockIdx.x & 7;
  const int b0 = btile * 16, t0 = chunk * LCH, nt0 = wv * 2;
  const int urow = tid >> 5, uuc = tid & 31;
  const float* ubase = u + (size_t)(b0 + urow) * (TT * NU) + uuc * 4;
  const int uoff = swz256(urow, uuc * 8);
  {
    f4 r0 = *(const f4*)(ubase + (size_t)t0 * NU);
    *(h4*)(ub + uoff) = h4cvt(r0);
  }
  f4 urA = *(const f4*)(ubase + (size_t)(t0 + 1) * NU);
  f4 urB = *(const f4*)(ubase + (size_t)(t0 + 2 < TT ? t0 + 2 : TT - 1) * NU);
  // per-lane G fragment offsets (A-operand: row = n, k = nu)
  const size_t go0 = (size_t)((nt0 + 0) * 16 + lr) * NU + g * 8;
  const size_t go1 = (size_t)((nt0 + 1) * 16 + lr) * NU + g * 8;
  h8 Ga[2][4], Gb[2][4];
  {
    const _Float16* gp = Gs16 + (size_t)31 * 32768;
#pragma unroll
    for (int kf = 0; kf < 4; ++kf) {
      Ga[0][kf] = *(const h8*)(gp + go0 + kf * 32);
      Ga[1][kf] = *(const h8*)(gp + go1 + kf * 32);
    }
  }
  f4 z4 = {0.f, 0.f, 0.f, 0.f};
  f4 xacc[2] = {z4, z4};
  __syncthreads();

#pragma unroll 2
  for (int i = 0; i < LCH; ++i) {
    const int p = i & 1;
    if (i < LCH - 1) {
      int nt = t0 + i + 3;
      if (nt > TT - 1) nt = TT - 1;
      if (p == 0) {
        *(h4*)(ub + 4096 + uoff) = h4cvt(urA);
        urA = *(const f4*)(ubase + (size_t)nt * NU);
      } else {
        *(h4*)(ub + uoff) = h4cvt(urB);
        urB = *(const f4*)(ubase + (size_t)nt * NU);
      }
    }
    // prefetch next step's G into alternate buffer
    int kn = 30 - i;
    if (kn < 0) kn = 0;
    const _Float16* gq = Gs16 + (size_t)kn * 32768;
    if (p == 0) {
#pragma unroll
      for (int kf = 0; kf < 4; ++kf) {
        Gb[0][kf] = *(const h8*)(gq + go0 + kf * 32);
        Gb[1][kf] = *(const h8*)(gq + go1 + kf * 32);
      }
    } else {
#pragma unroll
      for (int kf = 0; kf < 4; ++kf) {
        Ga[0][kf] = *(const h8*)(gq + go0 + kf * 32);
        Ga[1][kf] = *(const h8*)(gq + go1 + kf * 32);
      }
    }
    h8 uf[4];
#pragma unroll
    for (int kf = 0; kf < 4; ++kf)
      uf[kf] = *(const h8*)(ub + p * 4096 + swz256(lr, kf * 64 + g * 16));
    __builtin_amdgcn_s_setprio(1);
    if (p == 0) {
#pragma unroll
      for (int kf = 0; kf < 4; ++kf) {
        xacc[0] = mfma16(Ga[0][kf], uf[kf], xacc[0]);
        xacc[1] = mfma16(Ga[1][kf], uf[kf], xacc[1]);
      }
    } else {
#pragma unroll
      for (int kf = 0; kf < 4; ++kf) {
        xacc[0] = mfma16(Gb[0][kf], uf[kf], xacc[0]);
        xacc[1] = mfma16(Gb[1][kf], uf[kf], xacc[1]);
      }
    }
    __builtin_amdgcn_s_setprio(0);
    if (i < LCH - 1) LBAR();
  }
#pragma unroll
  for (int n2 = 0; n2 < 2; ++n2)
    *(f4*)(w + ((size_t)chunk * BSZ + b0 + lr) * NX + (nt0 + n2) * 16 + g * 4) = xacc[n2];
}

// ---------------- phase B: sequential chunk combine ----------------
__global__ __launch_bounds__(512, 2) void k_phB(const float* __restrict__ x0,
                                                const float* __restrict__ w,
                                                const _Float16* __restrict__ Ah16,
                                                float* __restrict__ xs) {
  __shared__ __align__(16) char xb[16384];
  const int tid = threadIdx.x, lane = tid & 63, wv = tid >> 6;
  const int g = lane >> 4, lr = lane & 15;
  const int b0 = blockIdx.x * 16, nt0 = wv * 2;
  h8 Ar[2][8];
#pragma unroll
  for (int n2 = 0; n2 < 2; ++n2)
#pragma unroll
    for (int kf = 0; kf < 8; ++kf) {
      Ar[n2][kf] = *(const h8*)(Ah16 + (size_t)((nt0 + n2) * 16 + lr) * NX + kf * 32 + g * 8);
      PIN(Ar[n2][kf]);
    }
  for (int s = 0; s < 8; ++s) {
    int e = tid + s * 512;
    int row = e >> 8, c = e & 255;
    xs[(size_t)(b0 + row) * NX + c] = x0[c];
  }
  h8 af[8];
#pragma unroll
  for (int kf = 0; kf < 8; ++kf) {
    const float* sp = x0 + kf * 32 + g * 8;
    af[kf] = cvt8(*(const f4*)sp, *(const f4*)(sp + 4));
  }
  f4 wl[2];
#pragma unroll
  for (int n2 = 0; n2 < 2; ++n2)
    wl[n2] = *(const f4*)(w + ((size_t)0 * BSZ + b0 + lr) * NX + (nt0 + n2) * 16 + g * 4);
  f4 z4 = {0.f, 0.f, 0.f, 0.f};
  for (int k = 0; k < KCH - 1; ++k) {
    const int p = k & 1;
    f4 wn[2] = {z4, z4};
    if (k < KCH - 2) {
#pragma unroll
      for (int n2 = 0; n2 < 2; ++n2)
        wn[n2] = *(const f4*)(w + ((size_t)(k + 1) * BSZ + b0 + lr) * NX + (nt0 + n2) * 16 + g * 4);
    }
    f4 acc[2] = {z4, z4};
#pragma unroll
    for (int kf = 0; kf < 8; ++kf) {
      acc[0] = mfma16(Ar[0][kf], af[kf], acc[0]);
      acc[1] = mfma16(Ar[1][kf], af[kf], acc[1]);
    }
#pragma unroll
    for (int n2 = 0; n2 < 2; ++n2) {
      acc[n2] += wl[n2];
      *(f4*)(xs + ((size_t)(k + 1) * BSZ + b0 + lr) * NX + (nt0 + n2) * 16 + g * 4) = acc[n2];
    }
    if (k < KCH - 2) {
#pragma unroll
      for (int n2 = 0; n2 < 2; ++n2)
        *(h4*)(xb + (p ^ 1) * 8192 + lr * 512 + ((((nt0 + n2) * 32) + g * 8) ^ ((lr & 7) << 4))) =
            h4cvt(acc[n2]);
      LBAR();
#pragma unroll
      for (int kf = 0; kf < 8; ++kf)
        af[kf] = *(const h8*)(xb + (p ^ 1) * 8192 + lr * 512 + ((kf * 64 + g * 16) ^ ((lr & 7) << 4)));
    }
#pragma unroll
    for (int n2 = 0; n2 < 2; ++n2) wl[n2] = wn[n2];
  }
}

// ---------------- phase Y: true-init recurrence, emits exact y ----------------
__global__ __launch_bounds__(512, 2) void k_recY(const float* __restrict__ u,
                                                 const _Float16* __restrict__ A16,
                                                 const _Float16* __restrict__ B16,
                                                 const _Float16* __restrict__ CA16,
                                                 const _Float16* __restrict__ CBD16,
                                                 const float* __restrict__ xs,
                                                 float* __restrict__ out) {
  __shared__ __align__(16) char sm[24576];
  char* xb = sm;
  char* ub = sm + 16384;
  const int tid = threadIdx.x, lane = tid & 63, wv = tid >> 6;
  const int g = lane >> 4, lr = lane & 15;
  const int chunk = blockIdx.x >> 3, btile = blockIdx.x & 7;
  const int b0 = btile * 16, t0 = chunk * LCH, nt0 = wv * 2;

  h8 Ar[2][8], Bf[2][4], Cf[8], Df[4];
#pragma unroll
  for (int n2 = 0; n2 < 2; ++n2) {
#pragma unroll
    for (int kf = 0; kf < 8; ++kf) {
      Ar[n2][kf] = *(const h8*)(A16 + (size_t)((nt0 + n2) * 16 + lr) * NX + kf * 32 + g * 8);
      PIN(Ar[n2][kf]);
    }
#pragma unroll
    for (int kf = 0; kf < 4; ++kf) {
      Bf[n2][kf] = *(const h8*)(B16 + (size_t)((nt0 + n2) * 16 + lr) * NU + kf * 32 + g * 8);
      PIN(Bf[n2][kf]);
    }
  }
#pragma unroll
  for (int kf = 0; kf < 8; ++kf) {
    Cf[kf] = *(const h8*)(CA16 + (size_t)(wv * 16 + lr) * NX + kf * 32 + g * 8);
    PIN(Cf[kf]);
  }
#pragma unroll
  for (int kf = 0; kf < 4; ++kf) {
    Df[kf] = *(const h8*)(CBD16 + (size_t)(wv * 16 + lr) * NU + kf * 32 + g * 8);
    PIN(Df[kf]);
  }
  h8 af[8];
#pragma unroll
  for (int kf = 0; kf < 8; ++kf) {
    const float* sp = xs + ((size_t)chunk * BSZ + b0 + lr) * NX + kf * 32 + g * 8;
    af[kf] = cvt8(*(const f4*)sp, *(const f4*)(sp + 4));
  }
  const int urow = tid >> 5, uuc = tid & 31;
  const float* ubase = u + (size_t)(b0 + urow) * (TT * NU) + uuc * 4;
  const int uoff = swz256(urow, uuc * 8);
  float* obase = out + (size_t)(b0 + lr) * (TT * NY) + wv * 16 + g * 4;
  {
    f4 r0 = *(const f4*)(ubase + (size_t)t0 * NU);
    *(h4*)(ub + uoff) = h4cvt(r0);
  }
  f4 urA = *(const f4*)(ubase + (size_t)(t0 + 1) * NU);
  f4 urB = *(const f4*)(ubase + (size_t)(t0 + 2 < TT ? t0 + 2 : TT - 1) * NU);
  __syncthreads();

  f4 z4 = {0.f, 0.f, 0.f, 0.f};
#pragma unroll 2
  for (int i = 0; i < LCH; ++i) {
    const int p = i & 1;
    if (i < LCH - 1) {
      int nt = t0 + i + 3;
      if (nt > TT - 1) nt = TT - 1;
      if (p == 0) {
        *(h4*)(ub + 4096 + uoff) = h4cvt(urA);
        urA = *(const f4*)(ubase + (size_t)nt * NU);
      } else {
        *(h4*)(ub + uoff) = h4cvt(urB);
        urB = *(const f4*)(ubase + (size_t)nt * NU);
      }
    }
    h8 uf[4];
#pragma unroll
    for (int kf = 0; kf < 4; ++kf)
      uf[kf] = *(const h8*)(ub + p * 4096 + swz256(lr, kf * 64 + g * 16));
    if (i < LCH - 1) {
      __builtin_amdgcn_s_setprio(1);
      f4 xacc[2] = {z4, z4};
#pragma unroll
      for (int kf = 0; kf < 8; ++kf) {
        xacc[0] = mfma16(Ar[0][kf], af[kf], xacc[0]);
        xacc[1] = mfma16(Ar[1][kf], af[kf], xacc[1]);
      }
#pragma unroll
      for (int kf = 0; kf < 4; ++kf) {
        xacc[0] = mfma16(Bf[0][kf], uf[kf], xacc[0]);
        xacc[1] = mfma16(Bf[1][kf], uf[kf], xacc[1]);
      }
      __builtin_amdgcn_s_setprio(0);
#pragma unroll
      for (int n2 = 0; n2 < 2; ++n2)
        *(h4*)(xb + (p ^ 1) * 8192 + lr * 512 + ((((nt0 + n2) * 32) + g * 8) ^ ((lr & 7) << 4))) =
            h4cvt(xacc[n2]);
    }
    __builtin_amdgcn_s_setprio(1);
    f4 yacc = z4;
#pragma unroll
    for (int kf = 0; kf < 8; ++kf) yacc = mfma16(Cf[kf], af[kf], yacc);
#pragma unroll
    for (int kf = 0; kf < 4; ++kf) yacc = mfma16(Df[kf], uf[kf], yacc);
    __builtin_amdgcn_s_setprio(0);
    int t = t0 + i + 1;
    if (t < TT) *(f4*)(obase + (size_t)t * NY) = yacc;
    if (i < LCH - 1) {
      LBAR();
#pragma unroll
      for (int kf = 0; kf < 8; ++kf)
        af[kf] = *(const h8*)(xb + (p ^ 1) * 8192 + lr * 512 + ((kf * 64 + g * 16) ^ ((lr & 7) << 4)));
    }
  }
}

extern "C" void kernel_launch(void* const* d_in, const int* in_sizes, int n_in,
                              void* d_out, int out_size, void* d_ws, size_t ws_size,
                              hipStream_t stream) {
  const float* u  = (const float*)d_in[0];
  const float* M  = (const float*)d_in[1];
  const float* B  = (const float*)d_in[2];
  const float* C  = (const float*)d_in[3];
  const float* D  = (const float*)d_in[4];
  const float* x0 = (const float*)d_in[5];
  float* out = (float*)d_out;
  char* ws = (char*)d_ws;

  float* E    = (float*)(ws + 0L);
  float* F    = (float*)(ws + 256L * 1024);
  float* X1   = (float*)(ws + 512L * 1024);
  float* Y1   = (float*)(ws + 768L * 1024);
  float* X2   = (float*)(ws + 1024L * 1024);
  float* Y2   = (float*)(ws + 1280L * 1024);
  float* Amat = (float*)(ws + 1536L * 1024);
  float* P2   = (float*)(ws + 1792L * 1024);
  float* P4   = (float*)(ws + 2048L * 1024);
  float* P8   = (float*)(ws + 2304L * 1024);
  float* P16  = (float*)(ws + 2560L * 1024);
  _Float16* A16   = (_Float16*)(ws + 2816L * 1024);
  _Float16* Ah16  = (_Float16*)(ws + 2944L * 1024);
  _Float16* B16   = (_Float16*)(ws + 3072L * 1024);
  _Float16* CA16  = (_Float16*)(ws + 3136L * 1024);
  _Float16* CBD16 = (_Float16*)(ws + 3200L * 1024);
  float* Gs32 = (float*)(ws + 3328L * 1024);          // 4 MB (32 x 256 x 128 fp32)
  float* wbuf = (float*)(ws + 9408L * 1024);          // 8 MB
  float* xs   = (float*)(ws + 17600L * 1024);         // 8 MB
  _Float16* Gs16 = (_Float16*)(ws + 25792L * 1024);   // 2 MB (32 x 256 x 128 fp16)

  MMJob nil = {nullptr, nullptr, nullptr, nullptr, nullptr, 0, 0, 0, 0, 1};

  k_ef<<<224, 256, 0, stream>>>(M, B, C, D, x0, u, E, F, B16, out, Gs32, Gs16);
  k_ns0<<<128, 256, 0, stream>>>(E, X1, Y1);
  float *Xc = X1, *Yc = Y1, *Xn = X2, *Yn = Y2;
  for (int it = 0; it < 6; ++it) {
    MMJob jx = {Xc, Yc, nullptr, Xn, nullptr, 256, 256, 1, 0, 1};
    MMJob jy = {Yc, Yc, nullptr, Yn, nullptr, 256, 256, 1, 64, 1};
    k_mm<<<128, 256, 0, stream>>>(jx, jy, nil, nil, 2);
    float* t1 = Xc; Xc = Xn; Xn = t1;
    float* t2 = Yc; Yc = Yn; Yn = t2;
  }
  {  // A = E^-1 F
    MMJob ja = {Xc, F, nullptr, Amat, A16, 256, 256, 0, 0, 1};
    k_mm<<<64, 256, 0, stream>>>(ja, nil, nil, nil, 1);
  }
  {  // L1: A^2 ; G1 = A*G0 ; CA16 ; CBD16
    MMJob j0 = {Amat, Amat, nullptr, P2, nullptr, 256, 256, 0, 0, 1};
    MMJob j1 = {Amat, Gs32, nullptr, Gs32 + 32768, Gs16 + 32768, 256, 128, 0, 64, 1};
    MMJob j2 = {C, Amat, nullptr, nullptr, CA16, 128, 256, 0, 96, 1};
    MMJob j3 = {C, B, D, nullptr, CBD16, 128, 128, 0, 128, 1};
    k_mm<<<144, 256, 0, stream>>>(j0, j1, j2, j3, 4);
  }
  {  // L2: A^4 ; G[2:4] = A^2 * G[0:2]
    MMJob j0 = {P2, P2, nullptr, P4, nullptr, 256, 256, 0, 0, 1};
    MMJob j1 = {P2, Gs32, nullptr, Gs32 + 2 * 32768, Gs16 + 2 * 32768, 256, 128, 0, 64, 2};
    k_mm<<<128, 256, 0, stream>>>(j0, j1, nil, nil, 2);
  }
  {  // L3: A^8 ; G[4:8] = A^4 * G[0:4]
    MMJob j0 = {P4, P4, nullptr, P8, nullptr, 256, 256, 0, 0, 1};
    MMJob j1 = {P4, Gs32, nullptr, Gs32 + 4 * 32768, Gs16 + 4 * 32768, 256, 128, 0, 64, 4};
    k_mm<<<192, 256, 0, stream>>>(j0, j1, nil, nil, 2);
  }
  {  // L4: A^16 ; G[8:16] = A^8 * G[0:8]
    MMJob j0 = {P8, P8, nullptr, P16, nullptr, 256, 256, 0, 0, 1};
    MMJob j1 = {P8, Gs32, nullptr, Gs32 + 8 * 32768, Gs16 + 8 * 32768, 256, 128, 0, 64, 8};
    k_mm<<<320, 256, 0, stream>>>(j0, j1, nil, nil, 2);
  }
  {  // L5: A^32 -> Ah16 ; G[16:32] = A^16 * G[0:16]
    MMJob j0 = {P16, P16, nullptr, nullptr, Ah16, 256, 256, 0, 0, 1};
    MMJob j1 = {P16, Gs32, nullptr, Gs32 + 16 * 32768, Gs16 + 16 * 32768, 256, 128, 0, 64, 16};
    k_mm<<<576, 256, 0, stream>>>(j0, j1, nil, nil, 2);
  }

  k_gw<<<512, 512, 0, stream>>>(u, Gs16, wbuf);
  k_phB<<<8, 512, 0, stream>>>(x0, wbuf, Ah16, xs);
  k_recY<<<512, 512, 0, stream>>>(u, A16, B16, CA16, CBD16, xs, out);
}

// Round 13
// 406.089 us; speedup vs baseline: 1.0314x; 1.0314x over previous
//
#include <hip/hip_runtime.h>

#define NX 256
#define NU 128
#define NY 128
#define BSZ 128
#define TT 2048
#define LCH 32
#define KCH 64

typedef _Float16 h8 __attribute__((ext_vector_type(8)));
typedef _Float16 h4 __attribute__((ext_vector_type(4)));
typedef float f4 __attribute__((ext_vector_type(4)));

__device__ __forceinline__ f4 mfma16(h8 a, h8 b, f4 c) {
  return __builtin_amdgcn_mfma_f32_16x16x32_f16(a, b, c, 0, 0, 0);
}
#define PIN(x) asm volatile("" : "+v"(x))
#define LBAR() asm volatile("s_waitcnt lgkmcnt(0)\n\ts_barrier" ::: "memory")

__device__ __forceinline__ int swz256(int row, int bc) { return row * 256 + (bc ^ ((row & 7) << 4)); }

__device__ __forceinline__ h8 cvt8(f4 lo, f4 hi) {
  h8 h;
#pragma unroll
  for (int j = 0; j < 4; ++j) { h[j] = (_Float16)lo[j]; h[j + 4] = (_Float16)hi[j]; }
  return h;
}
__device__ __forceinline__ h4 h4cvt(f4 v) {
  h4 h;
#pragma unroll
  for (int j = 0; j < 4; ++j) h[j] = (_Float16)v[j];
  return h;
}
__device__ __forceinline__ h8 h8zero() {
  h8 h;
#pragma unroll
  for (int j = 0; j < 8; ++j) h[j] = (_Float16)0.0f;
  return h;
}

// ---- fp32 GEMM core: 32x32 tile, K=256, lda=256, dbuf K=64 rounds + reg prefetch ----
__device__ __forceinline__ void mm_core(const float* __restrict__ a, const float* __restrict__ b,
                                        int Nb, int i0, int j0, int tid,
                                        float (*As)[32][65], float (*Bs)[64][33],
                                        float acc[2][2]) {
  const int ar = tid >> 4, ac = (tid & 15) * 4;
  const int br = tid >> 3, bc = (tid & 7) * 4;
  const int tx = tid & 15, ty = tid >> 4;
  f4 pa0 = *(const f4*)(a + (size_t)(i0 + ar) * 256 + ac);
  f4 pa1 = *(const f4*)(a + (size_t)(i0 + ar + 16) * 256 + ac);
  f4 pb0 = *(const f4*)(b + (size_t)br * Nb + j0 + bc);
  f4 pb1 = *(const f4*)(b + (size_t)(br + 32) * Nb + j0 + bc);
  for (int r4 = 0; r4 < 4; ++r4) {
    const int bs = r4 & 1;
#pragma unroll
    for (int m = 0; m < 4; ++m) {
      As[bs][ar][ac + m] = pa0[m];
      As[bs][ar + 16][ac + m] = pa1[m];
      Bs[bs][br][bc + m] = pb0[m];
      Bs[bs][br + 32][bc + m] = pb1[m];
    }
    if (r4 < 3) {
      int kk = (r4 + 1) * 64;
      pa0 = *(const f4*)(a + (size_t)(i0 + ar) * 256 + kk + ac);
      pa1 = *(const f4*)(a + (size_t)(i0 + ar + 16) * 256 + kk + ac);
      pb0 = *(const f4*)(b + (size_t)(kk + br) * Nb + j0 + bc);
      pb1 = *(const f4*)(b + (size_t)(kk + br + 32) * Nb + j0 + bc);
    }
    __syncthreads();
#pragma unroll 8
    for (int k = 0; k < 64; ++k) {
      float a0 = As[bs][ty * 2][k], a1 = As[bs][ty * 2 + 1][k];
      float b0 = Bs[bs][k][tx * 2], b1 = Bs[bs][k][tx * 2 + 1];
      acc[0][0] += a0 * b0; acc[0][1] += a0 * b1;
      acc[1][0] += a1 * b0; acc[1][1] += a1 * b1;
    }
  }
}

// ---------------- E,F from M; y0 exact fp32; B16 cast ----------------
__global__ __launch_bounds__(256) void k_ef(const float* __restrict__ M, const float* __restrict__ B,
                                            const float* __restrict__ C, const float* __restrict__ D,
                                            const float* __restrict__ x0, const float* __restrict__ u,
                                            float* __restrict__ E, float* __restrict__ F,
                                            _Float16* __restrict__ B16, float* __restrict__ out) {
  const int tid = threadIdx.x;
  int z = blockIdx.x >> 6;
  if (z >= 2) {
    if (blockIdx.x < 192) {  // y0
      int idx = (blockIdx.x - 128) * 256 + tid;
      int b = idx >> 7, col = idx & 127;
      const float* crow = C + (size_t)col * 256;
      const float* drow = D + (size_t)col * 128;
      const float* ur = u + (size_t)b * (TT * NU);
      float s = 0.f;
#pragma unroll 8
      for (int j = 0; j < 256; j += 4) {
        f4 cv = *(const f4*)(crow + j);
        f4 xv = *(const f4*)(x0 + j);
        s += cv[0] * xv[0] + cv[1] * xv[1] + cv[2] * xv[2] + cv[3] * xv[3];
      }
#pragma unroll 8
      for (int j = 0; j < 128; j += 4) {
        f4 dv = *(const f4*)(drow + j);
        f4 uv = *(const f4*)(ur + j);
        s += dv[0] * uv[0] + dv[1] * uv[1] + dv[2] * uv[2] + dv[3] * uv[3];
      }
      out[(size_t)b * (TT * NY) + col] = s;
    } else {  // B16 cast: 32 blocks x 1024 elems
      int i = (blockIdx.x - 192) * 1024 + tid;
      B16[i] = (_Float16)B[i];
      B16[i + 256] = (_Float16)B[i + 256];
      B16[i + 512] = (_Float16)B[i + 512];
      B16[i + 768] = (_Float16)B[i + 768];
    }
    return;
  }
  __shared__ float Ps[2][32][65], Qs[2][32][65];
  int tile = blockIdx.x & 63;
  int i0 = (tile >> 3) * 32, j0 = (tile & 7) * 32;
  const int ar = tid >> 4, ac = (tid & 15) * 4;
  const int tx = tid & 15, ty = tid >> 4;
  float acc[2][2] = {{0.f, 0.f}, {0.f, 0.f}};
  int np = (z == 0) ? 2 : 1;
  int rc = 0;
  for (int p = 0; p < np; ++p) {
    int po = (z == 0) ? p * 256 : 256;
    int qo = (z == 0) ? p * 256 : 0;
    f4 p0 = *(const f4*)(M + (size_t)(i0 + po + ar) * 512 + ac);
    f4 p1 = *(const f4*)(M + (size_t)(i0 + po + ar + 16) * 512 + ac);
    f4 q0 = *(const f4*)(M + (size_t)(j0 + qo + ar) * 512 + ac);
    f4 q1 = *(const f4*)(M + (size_t)(j0 + qo + ar + 16) * 512 + ac);
    for (int kk = 0; kk < 512; kk += 64) {
      const int bs = rc & 1;
      ++rc;
#pragma unroll
      for (int m = 0; m < 4; ++m) {
        Ps[bs][ar][ac + m] = p0[m];
        Ps[bs][ar + 16][ac + m] = p1[m];
        Qs[bs][ar][ac + m] = q0[m];
        Qs[bs][ar + 16][ac + m] = q1[m];
      }
      if (kk < 448) {
        int k2 = kk + 64;
        p0 = *(const f4*)(M + (size_t)(i0 + po + ar) * 512 + k2 + ac);
        p1 = *(const f4*)(M + (size_t)(i0 + po + ar + 16) * 512 + k2 + ac);
        q0 = *(const f4*)(M + (size_t)(j0 + qo + ar) * 512 + k2 + ac);
        q1 = *(const f4*)(M + (size_t)(j0 + qo + ar + 16) * 512 + k2 + ac);
      }
      __syncthreads();
#pragma unroll 8
      for (int k = 0; k < 64; ++k) {
        float a0 = Ps[bs][ty * 2][k], a1 = Ps[bs][ty * 2 + 1][k];
        float b0 = Qs[bs][tx * 2][k], b1 = Qs[bs][tx * 2 + 1][k];
        acc[0][0] += a0 * b0; acc[0][1] += a0 * b1;
        acc[1][0] += a1 * b0; acc[1][1] += a1 * b1;
      }
    }
  }
#pragma unroll
  for (int ii = 0; ii < 2; ++ii)
#pragma unroll
    for (int jj = 0; jj < 2; ++jj) {
      int i = i0 + ty * 2 + ii, j = j0 + tx * 2 + jj;
      if (z == 0) {
        float v = 0.5f * acc[ii][jj];
        if (i == j) v += 1e-9f;
        E[i * 256 + j] = v;
      } else {
        F[i * 256 + j] = acc[ii][jj];
      }
    }
}

// ---------------- NS init ----------------
__global__ __launch_bounds__(256) void k_ns0(const float* __restrict__ E,
                                             float* __restrict__ X, float* __restrict__ Y) {
  __shared__ float As[2][32][65];
  __shared__ float Bs[2][64][33];
  __shared__ float s1[256], red[256];
  const int tid = threadIdx.x;
  {
    float s = 0.f;
    const float* row = E + (size_t)tid * 256;
#pragma unroll 8
    for (int j = 0; j < 256; j += 4) {
      f4 e = *(const f4*)(row + j);
      s += e[0] + e[1] + e[2] + e[3];
    }
    s1[tid] = s; red[tid] = s * s;
  }
  __syncthreads();
  for (int o = 128; o > 0; o >>= 1) { if (tid < o) red[tid] += red[tid + o]; __syncthreads(); }
  float n1 = red[0];
  __syncthreads();
  {
    float s = 0.f;
    const float* row = E + (size_t)tid * 256;
#pragma unroll 8
    for (int j = 0; j < 256; j += 4) {
      f4 e = *(const f4*)(row + j);
      f4 vv = *(const f4*)(&s1[j]);
      s += e[0] * vv[0] + e[1] * vv[1] + e[2] * vv[2] + e[3] * vv[3];
    }
    red[tid] = s * s;
  }
  __syncthreads();
  for (int o = 128; o > 0; o >>= 1) { if (tid < o) red[tid] += red[tid + o]; __syncthreads(); }
  float c = sqrtf(n1 / red[0]);
  __syncthreads();
  if (blockIdx.x < 64) {
    int i0 = (blockIdx.x >> 3) * 32, j0 = (blockIdx.x & 7) * 32;
    float acc[2][2] = {{0.f, 0.f}, {0.f, 0.f}};
    mm_core(E, E, 256, i0, j0, tid, As, Bs, acc);
    int tx = tid & 15, ty = tid >> 4;
#pragma unroll
    for (int ii = 0; ii < 2; ++ii)
#pragma unroll
      for (int jj = 0; jj < 2; ++jj) {
        int i = i0 + ty * 2 + ii, j = j0 + tx * 2 + jj;
        Y[(size_t)i * 256 + j] = 2.f * c * E[(size_t)i * 256 + j] - c * c * acc[ii][jj];
      }
  } else {
    int idx = (blockIdx.x - 64) * 1024 + tid * 4;
    int i = idx >> 8, j = idx & 255;
    f4 e = *(const f4*)(E + idx);
    f4 v;
#pragma unroll
    for (int m = 0; m < 4; ++m) v[m] = ((j + m) == i ? 2.f * c : 0.f) - c * c * e[m];
    *(f4*)(X + idx) = v;
  }
}

// ---------------- multi-job fp32 GEMM ----------------
struct MMJob {
  const float* a; const float* b; const float* add;
  float* d32; _Float16* d16;
  int M, N, mode, blk0;
};

__global__ __launch_bounds__(256) void k_mm(MMJob j0, MMJob j1, MMJob j2, int njobs) {
  __shared__ float As[2][32][65];
  __shared__ float Bs[2][64][33];
  const int tid = threadIdx.x;
  int bid = blockIdx.x;
  MMJob jb = j0;
  if (njobs > 1 && bid >= j1.blk0) jb = j1;
  if (njobs > 2 && bid >= j2.blk0) jb = j2;
  int rel = bid - jb.blk0;
  int ntile = jb.N >> 5;
  int i0 = (rel / ntile) * 32, j0g = (rel % ntile) * 32;
  float acc[2][2] = {{0.f, 0.f}, {0.f, 0.f}};
  mm_core(jb.a, jb.b, jb.N, i0, j0g, tid, As, Bs, acc);
  int tx = tid & 15, ty = tid >> 4;
#pragma unroll
  for (int ii = 0; ii < 2; ++ii)
#pragma unroll
    for (int jj = 0; jj < 2; ++jj) {
      int i = i0 + ty * 2 + ii, j = j0g + tx * 2 + jj;
      size_t o = (size_t)i * jb.N + j;
      float v = acc[ii][jj];
      if (jb.mode == 1) v = 2.f * jb.a[(size_t)i * 256 + j] - v;
      else if (jb.add) v += jb.add[o];
      if (jb.d32) jb.d32[o] = v;
      if (jb.d16) jb.d16[o] = (_Float16)v;
    }
}

// ---------------- phase W: zero-init chunk increments, 2 chunks per block interleaved ----------------
__global__ __launch_bounds__(512, 2) void k_recW(const float* __restrict__ u,
                                                 const _Float16* __restrict__ A16,
                                                 const _Float16* __restrict__ B16,
                                                 float* __restrict__ w) {
  __shared__ __align__(16) char sm[49152];
  char* xb0 = sm;           // chain0: 2 x [16][256] h16
  char* xb1 = sm + 16384;   // chain1
  char* ub0 = sm + 32768;   // chain0: 2 x [16][128] h16
  char* ub1 = sm + 40960;   // chain1
  const int tid = threadIdx.x, lane = tid & 63, wv = tid >> 6;
  const int g = lane >> 4, lr = lane & 15;
  const int c0 = blockIdx.x >> 3, c1 = c0 + 32, btile = blockIdx.x & 7;
  const int b0 = btile * 16, nt0 = wv * 2;
  const int t00 = c0 * LCH, t10 = c1 * LCH;

  h8 Ar[2][8], Bf[2][4];
#pragma unroll
  for (int n2 = 0; n2 < 2; ++n2) {
#pragma unroll
    for (int kf = 0; kf < 8; ++kf) {
      Ar[n2][kf] = *(const h8*)(A16 + (size_t)((nt0 + n2) * 16 + lr) * NX + kf * 32 + g * 8);
      PIN(Ar[n2][kf]);
    }
#pragma unroll
    for (int kf = 0; kf < 4; ++kf) {
      Bf[n2][kf] = *(const h8*)(B16 + (size_t)((nt0 + n2) * 16 + lr) * NU + kf * 32 + g * 8);
      PIN(Bf[n2][kf]);
    }
  }
  const int urow = tid >> 5, uuc = tid & 31;
  const float* ubase = u + (size_t)(b0 + urow) * (TT * NU) + uuc * 4;
  const int uoff = swz256(urow, uuc * 8);
  {
    f4 r0 = *(const f4*)(ubase + (size_t)t00 * NU);
    *(h4*)(ub0 + uoff) = h4cvt(r0);
    f4 r1 = *(const f4*)(ubase + (size_t)t10 * NU);
    *(h4*)(ub1 + uoff) = h4cvt(r1);
  }
  f4 uA0 = *(const f4*)(ubase + (size_t)(t00 + 1) * NU);
  f4 uB0 = *(const f4*)(ubase + (size_t)(t00 + 2) * NU);
  f4 uA1 = *(const f4*)(ubase + (size_t)(t10 + 1) * NU);
  f4 uB1 = *(const f4*)(ubase + (size_t)(t10 + 2 < TT ? t10 + 2 : TT - 1) * NU);
  h8 af0[8], af1[8];
#pragma unroll
  for (int kf = 0; kf < 8; ++kf) { af0[kf] = h8zero(); af1[kf] = h8zero(); }
  __syncthreads();

  f4 z4 = {0.f, 0.f, 0.f, 0.f};
  f4 xc0[2], xc1[2];
#pragma unroll 2
  for (int i = 0; i < LCH; ++i) {
    const int p = i & 1;
    if (i < LCH - 1) {
      int n0 = t00 + i + 3;
      int n1 = t10 + i + 3;
      if (n1 > TT - 1) n1 = TT - 1;
      if (p == 0) {
        *(h4*)(ub0 + 4096 + uoff) = h4cvt(uA0);
        uA0 = *(const f4*)(ubase + (size_t)n0 * NU);
        *(h4*)(ub1 + 4096 + uoff) = h4cvt(uA1);
        uA1 = *(const f4*)(ubase + (size_t)n1 * NU);
      } else {
        *(h4*)(ub0 + uoff) = h4cvt(uB0);
        uB0 = *(const f4*)(ubase + (size_t)n0 * NU);
        *(h4*)(ub1 + uoff) = h4cvt(uB1);
        uB1 = *(const f4*)(ubase + (size_t)n1 * NU);
      }
    }
    h8 uf0[4], uf1[4];
#pragma unroll
    for (int kf = 0; kf < 4; ++kf) {
      uf0[kf] = *(const h8*)(ub0 + p * 4096 + swz256(lr, kf * 64 + g * 16));
      uf1[kf] = *(const h8*)(ub1 + p * 4096 + swz256(lr, kf * 64 + g * 16));
    }
    __builtin_amdgcn_s_setprio(1);
    xc0[0] = z4; xc0[1] = z4; xc1[0] = z4; xc1[1] = z4;
#pragma unroll
    for (int kf = 0; kf < 8; ++kf) {
      xc0[0] = mfma16(Ar[0][kf], af0[kf], xc0[0]);
      xc1[0] = mfma16(Ar[0][kf], af1[kf], xc1[0]);
      xc0[1] = mfma16(Ar[1][kf], af0[kf], xc0[1]);
      xc1[1] = mfma16(Ar[1][kf], af1[kf], xc1[1]);
    }
#pragma unroll
    for (int kf = 0; kf < 4; ++kf) {
      xc0[0] = mfma16(Bf[0][kf], uf0[kf], xc0[0]);
      xc1[0] = mfma16(Bf[0][kf], uf1[kf], xc1[0]);
      xc0[1] = mfma16(Bf[1][kf], uf0[kf], xc0[1]);
      xc1[1] = mfma16(Bf[1][kf], uf1[kf], xc1[1]);
    }
    __builtin_amdgcn_s_setprio(0);
    if (i < LCH - 1) {
#pragma unroll
      for (int n2 = 0; n2 < 2; ++n2) {
        *(h4*)(xb0 + (p ^ 1) * 8192 + lr * 512 + ((((nt0 + n2) * 32) + g * 8) ^ ((lr & 7) << 4))) =
            h4cvt(xc0[n2]);
        *(h4*)(xb1 + (p ^ 1) * 8192 + lr * 512 + ((((nt0 + n2) * 32) + g * 8) ^ ((lr & 7) << 4))) =
            h4cvt(xc1[n2]);
      }
      LBAR();
#pragma unroll
      for (int kf = 0; kf < 8; ++kf) {
        af0[kf] = *(const h8*)(xb0 + (p ^ 1) * 8192 + lr * 512 + ((kf * 64 + g * 16) ^ ((lr & 7) << 4)));
        af1[kf] = *(const h8*)(xb1 + (p ^ 1) * 8192 + lr * 512 + ((kf * 64 + g * 16) ^ ((lr & 7) << 4)));
      }
    }
  }
#pragma unroll
  for (int n2 = 0; n2 < 2; ++n2) {
    *(f4*)(w + ((size_t)c0 * BSZ + b0 + lr) * NX + (nt0 + n2) * 16 + g * 4) = xc0[n2];
    *(f4*)(w + ((size_t)c1 * BSZ + b0 + lr) * NX + (nt0 + n2) * 16 + g * 4) = xc1[n2];
  }
}

// ---------------- phase B: sequential chunk combine ----------------
__global__ __launch_bounds__(512, 2) void k_phB(const float* __restrict__ x0,
                                                const float* __restrict__ w,
                                                const _Float16* __restrict__ Ah16,
                                                float* __restrict__ xs) {
  __shared__ __align__(16) char xb[16384];
  const int tid = threadIdx.x, lane = tid & 63, wv = tid >> 6;
  const int g = lane >> 4, lr = lane & 15;
  const int b0 = blockIdx.x * 16, nt0 = wv * 2;
  h8 Ar[2][8];
#pragma unroll
  for (int n2 = 0; n2 < 2; ++n2)
#pragma unroll
    for (int kf = 0; kf < 8; ++kf) {
      Ar[n2][kf] = *(const h8*)(Ah16 + (size_t)((nt0 + n2) * 16 + lr) * NX + kf * 32 + g * 8);
      PIN(Ar[n2][kf]);
    }
  for (int s = 0; s < 8; ++s) {
    int e = tid + s * 512;
    int row = e >> 8, c = e & 255;
    xs[(size_t)(b0 + row) * NX + c] = x0[c];
  }
  h8 af[8];
#pragma unroll
  for (int kf = 0; kf < 8; ++kf) {
    const float* sp = x0 + kf * 32 + g * 8;
    af[kf] = cvt8(*(const f4*)sp, *(const f4*)(sp + 4));
  }
  f4 wl[2];
#pragma unroll
  for (int n2 = 0; n2 < 2; ++n2)
    wl[n2] = *(const f4*)(w + ((size_t)0 * BSZ + b0 + lr) * NX + (nt0 + n2) * 16 + g * 4);
  f4 z4 = {0.f, 0.f, 0.f, 0.f};
  for (int k = 0; k < KCH - 1; ++k) {
    const int p = k & 1;
    f4 wn[2] = {z4, z4};
    if (k < KCH - 2) {
#pragma unroll
      for (int n2 = 0; n2 < 2; ++n2)
        wn[n2] = *(const f4*)(w + ((size_t)(k + 1) * BSZ + b0 + lr) * NX + (nt0 + n2) * 16 + g * 4);
    }
    f4 acc[2] = {z4, z4};
#pragma unroll
    for (int kf = 0; kf < 8; ++kf) {
      acc[0] = mfma16(Ar[0][kf], af[kf], acc[0]);
      acc[1] = mfma16(Ar[1][kf], af[kf], acc[1]);
    }
#pragma unroll
    for (int n2 = 0; n2 < 2; ++n2) {
      acc[n2] += wl[n2];
      *(f4*)(xs + ((size_t)(k + 1) * BSZ + b0 + lr) * NX + (nt0 + n2) * 16 + g * 4) = acc[n2];
    }
    if (k < KCH - 2) {
#pragma unroll
      for (int n2 = 0; n2 < 2; ++n2)
        *(h4*)(xb + (p ^ 1) * 8192 + lr * 512 + ((((nt0 + n2) * 32) + g * 8) ^ ((lr & 7) << 4))) =
            h4cvt(acc[n2]);
      LBAR();
#pragma unroll
      for (int kf = 0; kf < 8; ++kf)
        af[kf] = *(const h8*)(xb + (p ^ 1) * 8192 + lr * 512 + ((kf * 64 + g * 16) ^ ((lr & 7) << 4)));
    }
#pragma unroll
    for (int n2 = 0; n2 < 2; ++n2) wl[n2] = wn[n2];
  }
}

// ---------------- phase Y: true-init recurrence, 2 chunks per block interleaved ----------------
__global__ __launch_bounds__(512, 2) void k_recY(const float* __restrict__ u,
                                                 const _Float16* __restrict__ A16,
                                                 const _Float16* __restrict__ B16,
                                                 const _Float16* __restrict__ CA16,
                                                 const _Float16* __restrict__ CBD16,
                                                 const float* __restrict__ xs,
                                                 float* __restrict__ out) {
  __shared__ __align__(16) char sm[49152];
  char* xb0 = sm;
  char* xb1 = sm + 16384;
  char* ub0 = sm + 32768;
  char* ub1 = sm + 40960;
  const int tid = threadIdx.x, lane = tid & 63, wv = tid >> 6;
  const int g = lane >> 4, lr = lane & 15;
  const int c0 = blockIdx.x >> 3, c1 = c0 + 32, btile = blockIdx.x & 7;
  const int b0 = btile * 16, nt0 = wv * 2;
  const int t00 = c0 * LCH, t10 = c1 * LCH;

  h8 Ar[2][8], Bf[2][4], Cf[8], Df[4];
#pragma unroll
  for (int n2 = 0; n2 < 2; ++n2) {
#pragma unroll
    for (int kf = 0; kf < 8; ++kf) {
      Ar[n2][kf] = *(const h8*)(A16 + (size_t)((nt0 + n2) * 16 + lr) * NX + kf * 32 + g * 8);
      PIN(Ar[n2][kf]);
    }
#pragma unroll
    for (int kf = 0; kf < 4; ++kf) {
      Bf[n2][kf] = *(const h8*)(B16 + (size_t)((nt0 + n2) * 16 + lr) * NU + kf * 32 + g * 8);
      PIN(Bf[n2][kf]);
    }
  }
#pragma unroll
  for (int kf = 0; kf < 8; ++kf)
    Cf[kf] = *(const h8*)(CA16 + (size_t)(wv * 16 + lr) * NX + kf * 32 + g * 8);
#pragma unroll
  for (int kf = 0; kf < 4; ++kf)
    Df[kf] = *(const h8*)(CBD16 + (size_t)(wv * 16 + lr) * NU + kf * 32 + g * 8);
  h8 af0[8], af1[8];
#pragma unroll
  for (int kf = 0; kf < 8; ++kf) {
    const float* s0 = xs + ((size_t)c0 * BSZ + b0 + lr) * NX + kf * 32 + g * 8;
    af0[kf] = cvt8(*(const f4*)s0, *(const f4*)(s0 + 4));
    const float* s1 = xs + ((size_t)c1 * BSZ + b0 + lr) * NX + kf * 32 + g * 8;
    af1[kf] = cvt8(*(const f4*)s1, *(const f4*)(s1 + 4));
  }
  const int urow = tid >> 5, uuc = tid & 31;
  const float* ubase = u + (size_t)(b0 + urow) * (TT * NU) + uuc * 4;
  const int uoff = swz256(urow, uuc * 8);
  float* obase = out + (size_t)(b0 + lr) * (TT * NY) + wv * 16 + g * 4;
  {
    f4 r0 = *(const f4*)(ubase + (size_t)t00 * NU);
    *(h4*)(ub0 + uoff) = h4cvt(r0);
    f4 r1 = *(const f4*)(ubase + (size_t)t10 * NU);
    *(h4*)(ub1 + uoff) = h4cvt(r1);
  }
  f4 uA0 = *(const f4*)(ubase + (size_t)(t00 + 1) * NU);
  f4 uB0 = *(const f4*)(ubase + (size_t)(t00 + 2) * NU);
  f4 uA1 = *(const f4*)(ubase + (size_t)(t10 + 1) * NU);
  f4 uB1 = *(const f4*)(ubase + (size_t)(t10 + 2 < TT ? t10 + 2 : TT - 1) * NU);
  __syncthreads();

  f4 z4 = {0.f, 0.f, 0.f, 0.f};
#pragma unroll 2
  for (int i = 0; i < LCH; ++i) {
    const int p = i & 1;
    if (i < LCH - 1) {
      int n0 = t00 + i + 3;
      int n1 = t10 + i + 3;
      if (n1 > TT - 1) n1 = TT - 1;
      if (p == 0) {
        *(h4*)(ub0 + 4096 + uoff) = h4cvt(uA0);
        uA0 = *(const f4*)(ubase + (size_t)n0 * NU);
        *(h4*)(ub1 + 4096 + uoff) = h4cvt(uA1);
        uA1 = *(const f4*)(ubase + (size_t)n1 * NU);
      } else {
        *(h4*)(ub0 + uoff) = h4cvt(uB0);
        uB0 = *(const f4*)(ubase + (size_t)n0 * NU);
        *(h4*)(ub1 + uoff) = h4cvt(uB1);
        uB1 = *(const f4*)(ubase + (size_t)n1 * NU);
      }
    }
    h8 uf0[4], uf1[4];
#pragma unroll
    for (int kf = 0; kf < 4; ++kf) {
      uf0[kf] = *(const h8*)(ub0 + p * 4096 + swz256(lr, kf * 64 + g * 16));
      uf1[kf] = *(const h8*)(ub1 + p * 4096 + swz256(lr, kf * 64 + g * 16));
    }
    if (i < LCH - 1) {
      __builtin_amdgcn_s_setprio(1);
      f4 xc0[2] = {z4, z4}, xc1[2] = {z4, z4};
#pragma unroll
      for (int kf = 0; kf < 8; ++kf) {
        xc0[0] = mfma16(Ar[0][kf], af0[kf], xc0[0]);
        xc1[0] = mfma16(Ar[0][kf], af1[kf], xc1[0]);
        xc0[1] = mfma16(Ar[1][kf], af0[kf], xc0[1]);
        xc1[1] = mfma16(Ar[1][kf], af1[kf], xc1[1]);
      }
#pragma unroll
      for (int kf = 0; kf < 4; ++kf) {
        xc0[0] = mfma16(Bf[0][kf], uf0[kf], xc0[0]);
        xc1[0] = mfma16(Bf[0][kf], uf1[kf], xc1[0]);
        xc0[1] = mfma16(Bf[1][kf], uf0[kf], xc0[1]);
        xc1[1] = mfma16(Bf[1][kf], uf1[kf], xc1[1]);
      }
      __builtin_amdgcn_s_setprio(0);
#pragma unroll
      for (int n2 = 0; n2 < 2; ++n2) {
        *(h4*)(xb0 + (p ^ 1) * 8192 + lr * 512 + ((((nt0 + n2) * 32) + g * 8) ^ ((lr & 7) << 4))) =
            h4cvt(xc0[n2]);
        *(h4*)(xb1 + (p ^ 1) * 8192 + lr * 512 + ((((nt0 + n2) * 32) + g * 8) ^ ((lr & 7) << 4))) =
            h4cvt(xc1[n2]);
      }
    }
    __builtin_amdgcn_s_setprio(1);
    f4 y0 = z4, y1 = z4;
#pragma unroll
    for (int kf = 0; kf < 8; ++kf) {
      y0 = mfma16(Cf[kf], af0[kf], y0);
      y1 = mfma16(Cf[kf], af1[kf], y1);
    }
#pragma unroll
    for (int kf = 0; kf < 4; ++kf) {
      y0 = mfma16(Df[kf], uf0[kf], y0);
      y1 = mfma16(Df[kf], uf1[kf], y1);
    }
    __builtin_amdgcn_s_setprio(0);
    int ta = t00 + i + 1, tb = t10 + i + 1;
    *(f4*)(obase + (size_t)ta * NY) = y0;
    if (tb < TT) *(f4*)(obase + (size_t)tb * NY) = y1;
    if (i < LCH - 1) {
      LBAR();
#pragma unroll
      for (int kf = 0; kf < 8; ++kf) {
        af0[kf] = *(const h8*)(xb0 + (p ^ 1) * 8192 + lr * 512 + ((kf * 64 + g * 16) ^ ((lr & 7) << 4)));
        af1[kf] = *(const h8*)(xb1 + (p ^ 1) * 8192 + lr * 512 + ((kf * 64 + g * 16) ^ ((lr & 7) << 4)));
      }
    }
  }
}

extern "C" void kernel_launch(void* const* d_in, const int* in_sizes, int n_in,
                              void* d_out, int out_size, void* d_ws, size_t ws_size,
                              hipStream_t stream) {
  const float* u  = (const float*)d_in[0];
  const float* M  = (const float*)d_in[1];
  const float* B  = (const float*)d_in[2];
  const float* C  = (const float*)d_in[3];
  const float* D  = (const float*)d_in[4];
  const float* x0 = (const float*)d_in[5];
  float* out = (float*)d_out;
  char* ws = (char*)d_ws;

  float* E    = (float*)(ws + 0L);
  float* F    = (float*)(ws + 256L * 1024);
  float* X1   = (float*)(ws + 512L * 1024);
  float* Y1   = (float*)(ws + 768L * 1024);
  float* X2   = (float*)(ws + 1024L * 1024);
  float* Y2   = (float*)(ws + 1280L * 1024);
  float* Amat = (float*)(ws + 1536L * 1024);
  float* P2   = (float*)(ws + 1792L * 1024);
  float* P4   = (float*)(ws + 2048L * 1024);
  float* P8   = (float*)(ws + 2304L * 1024);
  float* P16  = (float*)(ws + 2560L * 1024);
  _Float16* A16   = (_Float16*)(ws + 2816L * 1024);
  _Float16* Ah16  = (_Float16*)(ws + 2944L * 1024);
  _Float16* B16   = (_Float16*)(ws + 3072L * 1024);
  _Float16* CA16  = (_Float16*)(ws + 3136L * 1024);
  _Float16* CBD16 = (_Float16*)(ws + 3200L * 1024);
  float* wbuf = (float*)(ws + 9408L * 1024);           // 8 MB
  float* xs   = (float*)(ws + 17600L * 1024);          // 8 MB

  MMJob nil = {nullptr, nullptr, nullptr, nullptr, nullptr, 0, 0, 0, 0};

  k_ef<<<224, 256, 0, stream>>>(M, B, C, D, x0, u, E, F, B16, out);
  k_ns0<<<128, 256, 0, stream>>>(E, X1, Y1);
  float *Xc = X1, *Yc = Y1, *Xn = X2, *Yn = Y2;
  for (int it = 0; it < 6; ++it) {
    MMJob jx = {Xc, Yc, nullptr, Xn, nullptr, 256, 256, 1, 0};
    MMJob jy = {Yc, Yc, nullptr, Yn, nullptr, 256, 256, 1, 64};
    k_mm<<<128, 256, 0, stream>>>(jx, jy, nil, 2);
    float* t1 = Xc; Xc = Xn; Xn = t1;
    float* t2 = Yc; Yc = Yn; Yn = t2;
  }
  {  // A = E^-1 F
    MMJob ja = {Xc, F, nullptr, Amat, A16, 256, 256, 0, 0};
    k_mm<<<64, 256, 0, stream>>>(ja, nil, nil, 1);
  }
  {  // A^2 ; CA -> CA16 ; CBD = C B + D -> CBD16
    MMJob j0 = {Amat, Amat, nullptr, P2, nullptr, 256, 256, 0, 0};
    MMJob j1 = {C, Amat, nullptr, nullptr, CA16, 128, 256, 0, 64};
    MMJob j2 = {C, B, D, nullptr, CBD16, 128, 128, 0, 96};
    k_mm<<<112, 256, 0, stream>>>(j0, j1, j2, 3);
  }
  {  // A^4
    MMJob j0 = {P2, P2, nullptr, P4, nullptr, 256, 256, 0, 0};
    k_mm<<<64, 256, 0, stream>>>(j0, nil, nil, 1);
  }
  {  // A^8
    MMJob j0 = {P4, P4, nullptr, P8, nullptr, 256, 256, 0, 0};
    k_mm<<<64, 256, 0, stream>>>(j0, nil, nil, 1);
  }
  {  // A^16
    MMJob j0 = {P8, P8, nullptr, P16, nullptr, 256, 256, 0, 0};
    k_mm<<<64, 256, 0, stream>>>(j0, nil, nil, 1);
  }
  {  // A^32 -> Ah16
    MMJob j0 = {P16, P16, nullptr, nullptr, Ah16, 256, 256, 0, 0};
    k_mm<<<64, 256, 0, stream>>>(j0, nil, nil, 1);
  }

  k_recW<<<256, 512, 0, stream>>>(u, A16, B16, wbuf);
  k_phB<<<8, 512, 0, stream>>>(x0, wbuf, Ah16, xs);
  k_recY<<<256, 512, 0, stream>>>(u, A16, B16, CA16, CBD16, xs, out);
}

// Round 14
// 365.174 us; speedup vs baseline: 1.1470x; 1.1120x over previous
//
#include <hip/hip_runtime.h>

#define NX 256
#define NU 128
#define NY 128
#define BSZ 128
#define TT 2048
#define LCH 32
#define KCH 64

typedef _Float16 h8 __attribute__((ext_vector_type(8)));
typedef _Float16 h4 __attribute__((ext_vector_type(4)));
typedef float f4 __attribute__((ext_vector_type(4)));

__device__ __forceinline__ f4 mfma16(h8 a, h8 b, f4 c) {
  return __builtin_amdgcn_mfma_f32_16x16x32_f16(a, b, c, 0, 0, 0);
}
#define PIN(x) asm volatile("" : "+v"(x))
#define LBAR() asm volatile("s_waitcnt lgkmcnt(0)\n\ts_barrier" ::: "memory")

__device__ __forceinline__ int swz256(int row, int bc) { return row * 256 + (bc ^ ((row & 7) << 4)); }

__device__ __forceinline__ h8 cvt8(f4 lo, f4 hi) {
  h8 h;
#pragma unroll
  for (int j = 0; j < 4; ++j) { h[j] = (_Float16)lo[j]; h[j + 4] = (_Float16)hi[j]; }
  return h;
}
__device__ __forceinline__ h4 h4cvt(f4 v) {
  h4 h;
#pragma unroll
  for (int j = 0; j < 4; ++j) h[j] = (_Float16)v[j];
  return h;
}
__device__ __forceinline__ h8 h8zero() {
  h8 h;
#pragma unroll
  for (int j = 0; j < 8; ++j) h[j] = (_Float16)0.0f;
  return h;
}

// ---- fp32 GEMM core: 32x32 tile, K=256, lda=256, dbuf K=64 rounds + reg prefetch ----
__device__ __forceinline__ void mm_core(const float* __restrict__ a, const float* __restrict__ b,
                                        int Nb, int i0, int j0, int tid,
                                        float (*As)[32][65], float (*Bs)[64][33],
                                        float acc[2][2]) {
  const int ar = tid >> 4, ac = (tid & 15) * 4;
  const int br = tid >> 3, bc = (tid & 7) * 4;
  const int tx = tid & 15, ty = tid >> 4;
  f4 pa0 = *(const f4*)(a + (size_t)(i0 + ar) * 256 + ac);
  f4 pa1 = *(const f4*)(a + (size_t)(i0 + ar + 16) * 256 + ac);
  f4 pb0 = *(const f4*)(b + (size_t)br * Nb + j0 + bc);
  f4 pb1 = *(const f4*)(b + (size_t)(br + 32) * Nb + j0 + bc);
  for (int r4 = 0; r4 < 4; ++r4) {
    const int bs = r4 & 1;
#pragma unroll
    for (int m = 0; m < 4; ++m) {
      As[bs][ar][ac + m] = pa0[m];
      As[bs][ar + 16][ac + m] = pa1[m];
      Bs[bs][br][bc + m] = pb0[m];
      Bs[bs][br + 32][bc + m] = pb1[m];
    }
    if (r4 < 3) {
      int kk = (r4 + 1) * 64;
      pa0 = *(const f4*)(a + (size_t)(i0 + ar) * 256 + kk + ac);
      pa1 = *(const f4*)(a + (size_t)(i0 + ar + 16) * 256 + kk + ac);
      pb0 = *(const f4*)(b + (size_t)(kk + br) * Nb + j0 + bc);
      pb1 = *(const f4*)(b + (size_t)(kk + br + 32) * Nb + j0 + bc);
    }
    __syncthreads();
#pragma unroll 8
    for (int k = 0; k < 64; ++k) {
      float a0 = As[bs][ty * 2][k], a1 = As[bs][ty * 2 + 1][k];
      float b0 = Bs[bs][k][tx * 2], b1 = Bs[bs][k][tx * 2 + 1];
      acc[0][0] += a0 * b0; acc[0][1] += a0 * b1;
      acc[1][0] += a1 * b0; acc[1][1] += a1 * b1;
    }
  }
}

// ---------------- E,F from M; y0 exact fp32; B16 cast ----------------
__global__ __launch_bounds__(256) void k_ef(const float* __restrict__ M, const float* __restrict__ B,
                                            const float* __restrict__ C, const float* __restrict__ D,
                                            const float* __restrict__ x0, const float* __restrict__ u,
                                            float* __restrict__ E, float* __restrict__ F,
                                            _Float16* __restrict__ B16, float* __restrict__ out) {
  const int tid = threadIdx.x;
  int z = blockIdx.x >> 6;
  if (z >= 2) {
    if (blockIdx.x < 192) {  // y0
      int idx = (blockIdx.x - 128) * 256 + tid;
      int b = idx >> 7, col = idx & 127;
      const float* crow = C + (size_t)col * 256;
      const float* drow = D + (size_t)col * 128;
      const float* ur = u + (size_t)b * (TT * NU);
      float s = 0.f;
#pragma unroll 8
      for (int j = 0; j < 256; j += 4) {
        f4 cv = *(const f4*)(crow + j);
        f4 xv = *(const f4*)(x0 + j);
        s += cv[0] * xv[0] + cv[1] * xv[1] + cv[2] * xv[2] + cv[3] * xv[3];
      }
#pragma unroll 8
      for (int j = 0; j < 128; j += 4) {
        f4 dv = *(const f4*)(drow + j);
        f4 uv = *(const f4*)(ur + j);
        s += dv[0] * uv[0] + dv[1] * uv[1] + dv[2] * uv[2] + dv[3] * uv[3];
      }
      out[(size_t)b * (TT * NY) + col] = s;
    } else {  // B16 cast
      int i = (blockIdx.x - 192) * 1024 + tid;
      B16[i] = (_Float16)B[i];
      B16[i + 256] = (_Float16)B[i + 256];
      B16[i + 512] = (_Float16)B[i + 512];
      B16[i + 768] = (_Float16)B[i + 768];
    }
    return;
  }
  __shared__ float Ps[2][32][65], Qs[2][32][65];
  int tile = blockIdx.x & 63;
  int i0 = (tile >> 3) * 32, j0 = (tile & 7) * 32;
  const int ar = tid >> 4, ac = (tid & 15) * 4;
  const int tx = tid & 15, ty = tid >> 4;
  float acc[2][2] = {{0.f, 0.f}, {0.f, 0.f}};
  int np = (z == 0) ? 2 : 1;
  int rc = 0;
  for (int p = 0; p < np; ++p) {
    int po = (z == 0) ? p * 256 : 256;
    int qo = (z == 0) ? p * 256 : 0;
    f4 p0 = *(const f4*)(M + (size_t)(i0 + po + ar) * 512 + ac);
    f4 p1 = *(const f4*)(M + (size_t)(i0 + po + ar + 16) * 512 + ac);
    f4 q0 = *(const f4*)(M + (size_t)(j0 + qo + ar) * 512 + ac);
    f4 q1 = *(const f4*)(M + (size_t)(j0 + qo + ar + 16) * 512 + ac);
    for (int kk = 0; kk < 512; kk += 64) {
      const int bs = rc & 1;
      ++rc;
#pragma unroll
      for (int m = 0; m < 4; ++m) {
        Ps[bs][ar][ac + m] = p0[m];
        Ps[bs][ar + 16][ac + m] = p1[m];
        Qs[bs][ar][ac + m] = q0[m];
        Qs[bs][ar + 16][ac + m] = q1[m];
      }
      if (kk < 448) {
        int k2 = kk + 64;
        p0 = *(const f4*)(M + (size_t)(i0 + po + ar) * 512 + k2 + ac);
        p1 = *(const f4*)(M + (size_t)(i0 + po + ar + 16) * 512 + k2 + ac);
        q0 = *(const f4*)(M + (size_t)(j0 + qo + ar) * 512 + k2 + ac);
        q1 = *(const f4*)(M + (size_t)(j0 + qo + ar + 16) * 512 + k2 + ac);
      }
      __syncthreads();
#pragma unroll 8
      for (int k = 0; k < 64; ++k) {
        float a0 = Ps[bs][ty * 2][k], a1 = Ps[bs][ty * 2 + 1][k];
        float b0 = Qs[bs][tx * 2][k], b1 = Qs[bs][tx * 2 + 1][k];
        acc[0][0] += a0 * b0; acc[0][1] += a0 * b1;
        acc[1][0] += a1 * b0; acc[1][1] += a1 * b1;
      }
    }
  }
#pragma unroll
  for (int ii = 0; ii < 2; ++ii)
#pragma unroll
    for (int jj = 0; jj < 2; ++jj) {
      int i = i0 + ty * 2 + ii, j = j0 + tx * 2 + jj;
      if (z == 0) {
        float v = 0.5f * acc[ii][jj];
        if (i == j) v += 1e-9f;
        E[i * 256 + j] = v;
      } else {
        F[i * 256 + j] = acc[ii][jj];
      }
    }
}

// ---------------- NS init ----------------
__global__ __launch_bounds__(256) void k_ns0(const float* __restrict__ E,
                                             float* __restrict__ X, float* __restrict__ Y) {
  __shared__ float As[2][32][65];
  __shared__ float Bs[2][64][33];
  __shared__ float s1[256], red[256];
  const int tid = threadIdx.x;
  {
    float s = 0.f;
    const float* row = E + (size_t)tid * 256;
#pragma unroll 8
    for (int j = 0; j < 256; j += 4) {
      f4 e = *(const f4*)(row + j);
      s += e[0] + e[1] + e[2] + e[3];
    }
    s1[tid] = s; red[tid] = s * s;
  }
  __syncthreads();
  for (int o = 128; o > 0; o >>= 1) { if (tid < o) red[tid] += red[tid + o]; __syncthreads(); }
  float n1 = red[0];
  __syncthreads();
  {
    float s = 0.f;
    const float* row = E + (size_t)tid * 256;
#pragma unroll 8
    for (int j = 0; j < 256; j += 4) {
      f4 e = *(const f4*)(row + j);
      f4 vv = *(const f4*)(&s1[j]);
      s += e[0] * vv[0] + e[1] * vv[1] + e[2] * vv[2] + e[3] * vv[3];
    }
    red[tid] = s * s;
  }
  __syncthreads();
  for (int o = 128; o > 0; o >>= 1) { if (tid < o) red[tid] += red[tid + o]; __syncthreads(); }
  float c = sqrtf(n1 / red[0]);
  __syncthreads();
  if (blockIdx.x < 64) {
    int i0 = (blockIdx.x >> 3) * 32, j0 = (blockIdx.x & 7) * 32;
    float acc[2][2] = {{0.f, 0.f}, {0.f, 0.f}};
    mm_core(E, E, 256, i0, j0, tid, As, Bs, acc);
    int tx = tid & 15, ty = tid >> 4;
#pragma unroll
    for (int ii = 0; ii < 2; ++ii)
#pragma unroll
      for (int jj = 0; jj < 2; ++jj) {
        int i = i0 + ty * 2 + ii, j = j0 + tx * 2 + jj;
        Y[(size_t)i * 256 + j] = 2.f * c * E[(size_t)i * 256 + j] - c * c * acc[ii][jj];
      }
  } else {
    int idx = (blockIdx.x - 64) * 1024 + tid * 4;
    int i = idx >> 8, j = idx & 255;
    f4 e = *(const f4*)(E + idx);
    f4 v;
#pragma unroll
    for (int m = 0; m < 4; ++m) v[m] = ((j + m) == i ? 2.f * c : 0.f) - c * c * e[m];
    *(f4*)(X + idx) = v;
  }
}

// ---------------- multi-job fp32 GEMM ----------------
struct MMJob {
  const float* a; const float* b; const float* add;
  float* d32; _Float16* d16;
  int M, N, mode, blk0;
};

__global__ __launch_bounds__(256) void k_mm(MMJob j0, MMJob j1, MMJob j2, int njobs) {
  __shared__ float As[2][32][65];
  __shared__ float Bs[2][64][33];
  const int tid = threadIdx.x;
  int bid = blockIdx.x;
  MMJob jb = j0;
  if (njobs > 1 && bid >= j1.blk0) jb = j1;
  if (njobs > 2 && bid >= j2.blk0) jb = j2;
  int rel = bid - jb.blk0;
  int ntile = jb.N >> 5;
  int i0 = (rel / ntile) * 32, j0g = (rel % ntile) * 32;
  float acc[2][2] = {{0.f, 0.f}, {0.f, 0.f}};
  mm_core(jb.a, jb.b, jb.N, i0, j0g, tid, As, Bs, acc);
  int tx = tid & 15, ty = tid >> 4;
#pragma unroll
  for (int ii = 0; ii < 2; ++ii)
#pragma unroll
    for (int jj = 0; jj < 2; ++jj) {
      int i = i0 + ty * 2 + ii, j = j0g + tx * 2 + jj;
      size_t o = (size_t)i * jb.N + j;
      float v = acc[ii][jj];
      if (jb.mode == 1) v = 2.f * jb.a[(size_t)i * 256 + j] - v;
      else if (jb.add) v += jb.add[o];
      if (jb.d32) jb.d32[o] = v;
      if (jb.d16) jb.d16[o] = (_Float16)v;
    }
}

// ---------------- phase W: zero-init chunk increments w ; emits u16 byproduct ----------------
__global__ __launch_bounds__(512, 2) void k_recW(const float* __restrict__ u,
                                                 const _Float16* __restrict__ A16,
                                                 const _Float16* __restrict__ B16,
                                                 float* __restrict__ w,
                                                 _Float16* __restrict__ u16o) {
  __shared__ __align__(16) char sm[24576];
  char* xb = sm;
  char* ub = sm + 16384;
  const int tid = threadIdx.x, lane = tid & 63, wv = tid >> 6;
  const int g = lane >> 4, lr = lane & 15;
  const int chunk = blockIdx.x >> 3, btile = blockIdx.x & 7;
  const int b0 = btile * 16, t0 = chunk * LCH, nt0 = wv * 2;

  h8 Ar[2][8], Bf[2][4];
#pragma unroll
  for (int n2 = 0; n2 < 2; ++n2) {
#pragma unroll
    for (int kf = 0; kf < 8; ++kf) {
      Ar[n2][kf] = *(const h8*)(A16 + (size_t)((nt0 + n2) * 16 + lr) * NX + kf * 32 + g * 8);
      PIN(Ar[n2][kf]);
    }
#pragma unroll
    for (int kf = 0; kf < 4; ++kf) {
      Bf[n2][kf] = *(const h8*)(B16 + (size_t)((nt0 + n2) * 16 + lr) * NU + kf * 32 + g * 8);
      PIN(Bf[n2][kf]);
    }
  }
  const int urow = tid >> 5, uuc = tid & 31;
  const float* ubase = u + (size_t)(b0 + urow) * (TT * NU) + uuc * 4;
  _Float16* u16g = u16o ? (u16o + (size_t)(b0 + urow) * (TT * NU) + uuc * 4) : nullptr;
  const int uoff = swz256(urow, uuc * 8);
  {
    f4 r0 = *(const f4*)(ubase + (size_t)t0 * NU);
    h4 h0 = h4cvt(r0);
    *(h4*)(ub + uoff) = h0;
    if (u16g) *(h4*)(u16g + (size_t)t0 * NU) = h0;
  }
  f4 urA = *(const f4*)(ubase + (size_t)(t0 + 1) * NU);
  f4 urB = *(const f4*)(ubase + (size_t)(t0 + 2 < TT ? t0 + 2 : TT - 1) * NU);
  h8 af[8];
#pragma unroll
  for (int kf = 0; kf < 8; ++kf) af[kf] = h8zero();
  __syncthreads();

  f4 z4 = {0.f, 0.f, 0.f, 0.f};
  f4 xacc[2];
#pragma unroll 2
  for (int i = 0; i < LCH; ++i) {
    const int p = i & 1;
    if (i < LCH - 1) {
      int nt = t0 + i + 3;
      if (nt > TT - 1) nt = TT - 1;
      if (p == 0) {
        h4 hh = h4cvt(urA);
        *(h4*)(ub + 4096 + uoff) = hh;
        if (u16g) *(h4*)(u16g + (size_t)(t0 + i + 1) * NU) = hh;
        urA = *(const f4*)(ubase + (size_t)nt * NU);
      } else {
        h4 hh = h4cvt(urB);
        *(h4*)(ub + uoff) = hh;
        if (u16g) *(h4*)(u16g + (size_t)(t0 + i + 1) * NU) = hh;
        urB = *(const f4*)(ubase + (size_t)nt * NU);
      }
    }
    h8 uf[4];
#pragma unroll
    for (int kf = 0; kf < 4; ++kf)
      uf[kf] = *(const h8*)(ub + p * 4096 + swz256(lr, kf * 64 + g * 16));
    __builtin_amdgcn_s_setprio(1);
    xacc[0] = z4; xacc[1] = z4;
#pragma unroll
    for (int kf = 0; kf < 8; ++kf) {
      xacc[0] = mfma16(Ar[0][kf], af[kf], xacc[0]);
      xacc[1] = mfma16(Ar[1][kf], af[kf], xacc[1]);
    }
#pragma unroll
    for (int kf = 0; kf < 4; ++kf) {
      xacc[0] = mfma16(Bf[0][kf], uf[kf], xacc[0]);
      xacc[1] = mfma16(Bf[1][kf], uf[kf], xacc[1]);
    }
    __builtin_amdgcn_s_setprio(0);
    if (i < LCH - 1) {
#pragma unroll
      for (int n2 = 0; n2 < 2; ++n2)
        *(h4*)(xb + (p ^ 1) * 8192 + lr * 512 + ((((nt0 + n2) * 32) + g * 8) ^ ((lr & 7) << 4))) =
            h4cvt(xacc[n2]);
      LBAR();
#pragma unroll
      for (int kf = 0; kf < 8; ++kf)
        af[kf] = *(const h8*)(xb + (p ^ 1) * 8192 + lr * 512 + ((kf * 64 + g * 16) ^ ((lr & 7) << 4)));
    }
  }
#pragma unroll
  for (int n2 = 0; n2 < 2; ++n2)
    *(f4*)(w + ((size_t)chunk * BSZ + b0 + lr) * NX + (nt0 + n2) * 16 + g * 4) = xacc[n2];
}

// ---------------- phase B: sequential chunk combine ----------------
__global__ __launch_bounds__(512, 2) void k_phB(const float* __restrict__ x0,
                                                const float* __restrict__ w,
                                                const _Float16* __restrict__ Ah16,
                                                float* __restrict__ xs) {
  __shared__ __align__(16) char xb[16384];
  const int tid = threadIdx.x, lane = tid & 63, wv = tid >> 6;
  const int g = lane >> 4, lr = lane & 15;
  const int b0 = blockIdx.x * 16, nt0 = wv * 2;
  h8 Ar[2][8];
#pragma unroll
  for (int n2 = 0; n2 < 2; ++n2)
#pragma unroll
    for (int kf = 0; kf < 8; ++kf) {
      Ar[n2][kf] = *(const h8*)(Ah16 + (size_t)((nt0 + n2) * 16 + lr) * NX + kf * 32 + g * 8);
      PIN(Ar[n2][kf]);
    }
  for (int s = 0; s < 8; ++s) {
    int e = tid + s * 512;
    int row = e >> 8, c = e & 255;
    xs[(size_t)(b0 + row) * NX + c] = x0[c];
  }
  h8 af[8];
#pragma unroll
  for (int kf = 0; kf < 8; ++kf) {
    const float* sp = x0 + kf * 32 + g * 8;
    af[kf] = cvt8(*(const f4*)sp, *(const f4*)(sp + 4));
  }
  f4 wl[2];
#pragma unroll
  for (int n2 = 0; n2 < 2; ++n2)
    wl[n2] = *(const f4*)(w + ((size_t)0 * BSZ + b0 + lr) * NX + (nt0 + n2) * 16 + g * 4);
  f4 z4 = {0.f, 0.f, 0.f, 0.f};
  for (int k = 0; k < KCH - 1; ++k) {
    const int p = k & 1;
    f4 wn[2] = {z4, z4};
    if (k < KCH - 2) {
#pragma unroll
      for (int n2 = 0; n2 < 2; ++n2)
        wn[n2] = *(const f4*)(w + ((size_t)(k + 1) * BSZ + b0 + lr) * NX + (nt0 + n2) * 16 + g * 4);
    }
    f4 acc[2] = {z4, z4};
#pragma unroll
    for (int kf = 0; kf < 8; ++kf) {
      acc[0] = mfma16(Ar[0][kf], af[kf], acc[0]);
      acc[1] = mfma16(Ar[1][kf], af[kf], acc[1]);
    }
#pragma unroll
    for (int n2 = 0; n2 < 2; ++n2) {
      acc[n2] += wl[n2];
      *(f4*)(xs + ((size_t)(k + 1) * BSZ + b0 + lr) * NX + (nt0 + n2) * 16 + g * 4) = acc[n2];
    }
    if (k < KCH - 2) {
#pragma unroll
      for (int n2 = 0; n2 < 2; ++n2)
        *(h4*)(xb + (p ^ 1) * 8192 + lr * 512 + ((((nt0 + n2) * 32) + g * 8) ^ ((lr & 7) << 4))) =
            h4cvt(acc[n2]);
      LBAR();
#pragma unroll
      for (int kf = 0; kf < 8; ++kf)
        af[kf] = *(const h8*)(xb + (p ^ 1) * 8192 + lr * 512 + ((kf * 64 + g * 16) ^ ((lr & 7) << 4)));
    }
#pragma unroll
    for (int n2 = 0; n2 < 2; ++n2) wl[n2] = wn[n2];
  }
}

// ---------------- phase Y: true-init recurrence, emits exact y ----------------
// DIRECT=1: u consumed as fp16 straight from global (u16), no LDS u staging.
template <int DIRECT>
__global__ __launch_bounds__(512, 2) void k_recY(const float* __restrict__ u,
                                                 const _Float16* __restrict__ u16,
                                                 const _Float16* __restrict__ A16,
                                                 const _Float16* __restrict__ B16,
                                                 const _Float16* __restrict__ CA16,
                                                 const _Float16* __restrict__ CBD16,
                                                 const float* __restrict__ xs,
                                                 float* __restrict__ out) {
  __shared__ __align__(16) char sm[24576];
  char* xb = sm;
  char* ub = sm + 16384;
  const int tid = threadIdx.x, lane = tid & 63, wv = tid >> 6;
  const int g = lane >> 4, lr = lane & 15;
  const int chunk = blockIdx.x >> 3, btile = blockIdx.x & 7;
  const int b0 = btile * 16, t0 = chunk * LCH, nt0 = wv * 2;

  h8 Ar[2][8], Bf[2][4], Cf[8], Df[4];
#pragma unroll
  for (int n2 = 0; n2 < 2; ++n2) {
#pragma unroll
    for (int kf = 0; kf < 8; ++kf) {
      Ar[n2][kf] = *(const h8*)(A16 + (size_t)((nt0 + n2) * 16 + lr) * NX + kf * 32 + g * 8);
      PIN(Ar[n2][kf]);
    }
#pragma unroll
    for (int kf = 0; kf < 4; ++kf) {
      Bf[n2][kf] = *(const h8*)(B16 + (size_t)((nt0 + n2) * 16 + lr) * NU + kf * 32 + g * 8);
      PIN(Bf[n2][kf]);
    }
  }
#pragma unroll
  for (int kf = 0; kf < 8; ++kf) {
    Cf[kf] = *(const h8*)(CA16 + (size_t)(wv * 16 + lr) * NX + kf * 32 + g * 8);
    PIN(Cf[kf]);
  }
#pragma unroll
  for (int kf = 0; kf < 4; ++kf) {
    Df[kf] = *(const h8*)(CBD16 + (size_t)(wv * 16 + lr) * NU + kf * 32 + g * 8);
    PIN(Df[kf]);
  }
  h8 af[8];
#pragma unroll
  for (int kf = 0; kf < 8; ++kf) {
    const float* sp = xs + ((size_t)chunk * BSZ + b0 + lr) * NX + kf * 32 + g * 8;
    af[kf] = cvt8(*(const f4*)sp, *(const f4*)(sp + 4));
  }
  float* obase = out + (size_t)(b0 + lr) * (TT * NY) + wv * 16 + g * 4;

  // u plumbing
  const int urow = tid >> 5, uuc = tid & 31;
  const float* ubase = u + (size_t)(b0 + urow) * (TT * NU) + uuc * 4;
  const int uoff = swz256(urow, uuc * 8);
  const _Float16* ub16 = u16 + (size_t)(b0 + lr) * (TT * NU) + g * 8;
  h8 ufA[4], ufB[4];
  f4 urA, urB;
  if constexpr (DIRECT) {
#pragma unroll
    for (int kf = 0; kf < 4; ++kf) {
      ufA[kf] = *(const h8*)(ub16 + (size_t)t0 * NU + kf * 32);
      ufB[kf] = *(const h8*)(ub16 + (size_t)(t0 + 1) * NU + kf * 32);
    }
    __syncthreads();  // xb not used yet; keeps waves aligned
  } else {
    f4 r0 = *(const f4*)(ubase + (size_t)t0 * NU);
    *(h4*)(ub + uoff) = h4cvt(r0);
    urA = *(const f4*)(ubase + (size_t)(t0 + 1) * NU);
    urB = *(const f4*)(ubase + (size_t)(t0 + 2 < TT ? t0 + 2 : TT - 1) * NU);
    __syncthreads();
  }

  f4 z4 = {0.f, 0.f, 0.f, 0.f};
#pragma unroll 2
  for (int i = 0; i < LCH; ++i) {
    const int p = i & 1;
    h8 uf[4];
    if constexpr (DIRECT) {
#pragma unroll
      for (int kf = 0; kf < 4; ++kf) uf[kf] = p ? ufB[kf] : ufA[kf];
    } else {
      if (i < LCH - 1) {
        int nt = t0 + i + 3;
        if (nt > TT - 1) nt = TT - 1;
        if (p == 0) {
          *(h4*)(ub + 4096 + uoff) = h4cvt(urA);
          urA = *(const f4*)(ubase + (size_t)nt * NU);
        } else {
          *(h4*)(ub + uoff) = h4cvt(urB);
          urB = *(const f4*)(ubase + (size_t)nt * NU);
        }
      }
#pragma unroll
      for (int kf = 0; kf < 4; ++kf)
        uf[kf] = *(const h8*)(ub + p * 4096 + swz256(lr, kf * 64 + g * 16));
    }
    // x-update first (shortens pre-barrier critical path)
    if (i < LCH - 1) {
      __builtin_amdgcn_s_setprio(1);
      f4 xacc[2] = {z4, z4};
#pragma unroll
      for (int kf = 0; kf < 8; ++kf) {
        xacc[0] = mfma16(Ar[0][kf], af[kf], xacc[0]);
        xacc[1] = mfma16(Ar[1][kf], af[kf], xacc[1]);
      }
#pragma unroll
      for (int kf = 0; kf < 4; ++kf) {
        xacc[0] = mfma16(Bf[0][kf], uf[kf], xacc[0]);
        xacc[1] = mfma16(Bf[1][kf], uf[kf], xacc[1]);
      }
      __builtin_amdgcn_s_setprio(0);
#pragma unroll
      for (int n2 = 0; n2 < 2; ++n2)
        *(h4*)(xb + (p ^ 1) * 8192 + lr * 512 + ((((nt0 + n2) * 32) + g * 8) ^ ((lr & 7) << 4))) =
            h4cvt(xacc[n2]);
    }
    __builtin_amdgcn_s_setprio(1);
    f4 yacc = z4;
#pragma unroll
    for (int kf = 0; kf < 8; ++kf) yacc = mfma16(Cf[kf], af[kf], yacc);
#pragma unroll
    for (int kf = 0; kf < 4; ++kf) yacc = mfma16(Df[kf], uf[kf], yacc);
    __builtin_amdgcn_s_setprio(0);
    int t = t0 + i + 1;
    if (t < TT) *(f4*)(obase + (size_t)t * NY) = yacc;
    if constexpr (DIRECT) {
      if (i < LCH - 2) {  // reload consumed buffer with t0+i+2 (always in-chunk)
        const _Float16* np = ub16 + (size_t)(t0 + i + 2) * NU;
#pragma unroll
        for (int kf = 0; kf < 4; ++kf) {
          if (p) ufB[kf] = *(const h8*)(np + kf * 32);
          else ufA[kf] = *(const h8*)(np + kf * 32);
        }
      }
    }
    if (i < LCH - 1) {
      LBAR();
#pragma unroll
      for (int kf = 0; kf < 8; ++kf)
        af[kf] = *(const h8*)(xb + (p ^ 1) * 8192 + lr * 512 + ((kf * 64 + g * 16) ^ ((lr & 7) << 4)));
    }
  }
}

extern "C" void kernel_launch(void* const* d_in, const int* in_sizes, int n_in,
                              void* d_out, int out_size, void* d_ws, size_t ws_size,
                              hipStream_t stream) {
  const float* u  = (const float*)d_in[0];
  const float* M  = (const float*)d_in[1];
  const float* B  = (const float*)d_in[2];
  const float* C  = (const float*)d_in[3];
  const float* D  = (const float*)d_in[4];
  const float* x0 = (const float*)d_in[5];
  float* out = (float*)d_out;
  char* ws = (char*)d_ws;

  float* E    = (float*)(ws + 0L);
  float* F    = (float*)(ws + 256L * 1024);
  float* X1   = (float*)(ws + 512L * 1024);
  float* Y1   = (float*)(ws + 768L * 1024);
  float* X2   = (float*)(ws + 1024L * 1024);
  float* Y2   = (float*)(ws + 1280L * 1024);
  float* Amat = (float*)(ws + 1536L * 1024);
  float* P2   = (float*)(ws + 1792L * 1024);
  float* P4   = (float*)(ws + 2048L * 1024);
  float* P8   = (float*)(ws + 2304L * 1024);
  float* P16  = (float*)(ws + 2560L * 1024);
  _Float16* A16   = (_Float16*)(ws + 2816L * 1024);
  _Float16* Ah16  = (_Float16*)(ws + 2944L * 1024);
  _Float16* B16   = (_Float16*)(ws + 3072L * 1024);
  _Float16* CA16  = (_Float16*)(ws + 3136L * 1024);
  _Float16* CBD16 = (_Float16*)(ws + 3200L * 1024);
  float* wbuf = (float*)(ws + 9408L * 1024);           // 8 MB
  float* xs   = (float*)(ws + 17600L * 1024);          // 8 MB
  // u16 needs 64 MB at offset 26 MB -> total 90 MB
  const size_t u16_off = 26624L * 1024;
  bool big = ws_size >= u16_off + (size_t)64 * 1024 * 1024;
  _Float16* u16 = big ? (_Float16*)(ws + u16_off) : nullptr;

  MMJob nil = {nullptr, nullptr, nullptr, nullptr, nullptr, 0, 0, 0, 0};

  k_ef<<<224, 256, 0, stream>>>(M, B, C, D, x0, u, E, F, B16, out);
  k_ns0<<<128, 256, 0, stream>>>(E, X1, Y1);
  float *Xc = X1, *Yc = Y1, *Xn = X2, *Yn = Y2;
  for (int it = 0; it < 6; ++it) {
    MMJob jx = {Xc, Yc, nullptr, Xn, nullptr, 256, 256, 1, 0};
    MMJob jy = {Yc, Yc, nullptr, Yn, nullptr, 256, 256, 1, 64};
    k_mm<<<128, 256, 0, stream>>>(jx, jy, nil, 2);
    float* t1 = Xc; Xc = Xn; Xn = t1;
    float* t2 = Yc; Yc = Yn; Yn = t2;
  }
  {  // A = E^-1 F
    MMJob ja = {Xc, F, nullptr, Amat, A16, 256, 256, 0, 0};
    k_mm<<<64, 256, 0, stream>>>(ja, nil, nil, 1);
  }
  {  // A^2 ; CA -> CA16 ; CBD = C B + D -> CBD16
    MMJob j0 = {Amat, Amat, nullptr, P2, nullptr, 256, 256, 0, 0};
    MMJob j1 = {C, Amat, nullptr, nullptr, CA16, 128, 256, 0, 64};
    MMJob j2 = {C, B, D, nullptr, CBD16, 128, 128, 0, 96};
    k_mm<<<112, 256, 0, stream>>>(j0, j1, j2, 3);
  }
  {  // A^4
    MMJob j0 = {P2, P2, nullptr, P4, nullptr, 256, 256, 0, 0};
    k_mm<<<64, 256, 0, stream>>>(j0, nil, nil, 1);
  }
  {  // A^8
    MMJob j0 = {P4, P4, nullptr, P8, nullptr, 256, 256, 0, 0};
    k_mm<<<64, 256, 0, stream>>>(j0, nil, nil, 1);
  }
  {  // A^16
    MMJob j0 = {P8, P8, nullptr, P16, nullptr, 256, 256, 0, 0};
    k_mm<<<64, 256, 0, stream>>>(j0, nil, nil, 1);
  }
  {  // A^32 -> Ah16
    MMJob j0 = {P16, P16, nullptr, nullptr, Ah16, 256, 256, 0, 0};
    k_mm<<<64, 256, 0, stream>>>(j0, nil, nil, 1);
  }

  k_recW<<<512, 512, 0, stream>>>(u, A16, B16, wbuf, u16);
  k_phB<<<8, 512, 0, stream>>>(x0, wbuf, Ah16, xs);
  if (big)
    k_recY<1><<<512, 512, 0, stream>>>(u, u16, A16, B16, CA16, CBD16, xs, out);
  else
    k_recY<0><<<512, 512, 0, stream>>>(u, u16, A16, B16, CA16, CBD16, xs, out);
}

// Round 15
// 347.701 us; speedup vs baseline: 1.2046x; 1.0503x over previous
//
#include <hip/hip_runtime.h>

#define NX 256
#define NU 128
#define NY 128
#define BSZ 128
#define TT 2048
#define LCH 32
#define KCH 64

typedef _Float16 h8 __attribute__((ext_vector_type(8)));
typedef _Float16 h4 __attribute__((ext_vector_type(4)));
typedef float f4 __attribute__((ext_vector_type(4)));

__device__ __forceinline__ f4 mfma16(h8 a, h8 b, f4 c) {
  return __builtin_amdgcn_mfma_f32_16x16x32_f16(a, b, c, 0, 0, 0);
}
#define PIN(x) asm volatile("" : "+v"(x))
#define LBAR() asm volatile("s_waitcnt lgkmcnt(0)\n\ts_barrier" ::: "memory")

__device__ __forceinline__ int swz256(int row, int bc) { return row * 256 + (bc ^ ((row & 7) << 4)); }

__device__ __forceinline__ h8 cvt8(f4 lo, f4 hi) {
  h8 h;
#pragma unroll
  for (int j = 0; j < 4; ++j) { h[j] = (_Float16)lo[j]; h[j + 4] = (_Float16)hi[j]; }
  return h;
}
__device__ __forceinline__ h4 h4cvt(f4 v) {
  h4 h;
#pragma unroll
  for (int j = 0; j < 4; ++j) h[j] = (_Float16)v[j];
  return h;
}
__device__ __forceinline__ h8 h8zero() {
  h8 h;
#pragma unroll
  for (int j = 0; j < 8; ++j) h[j] = (_Float16)0.0f;
  return h;
}

// ---- fp32 GEMM core: 32x32 tile, K=256, lda=256, dbuf K=64 rounds + reg prefetch ----
__device__ __forceinline__ void mm_core(const float* __restrict__ a, const float* __restrict__ b,
                                        int Nb, int i0, int j0, int tid,
                                        float (*As)[32][65], float (*Bs)[64][33],
                                        float acc[2][2]) {
  const int ar = tid >> 4, ac = (tid & 15) * 4;
  const int br = tid >> 3, bc = (tid & 7) * 4;
  const int tx = tid & 15, ty = tid >> 4;
  f4 pa0 = *(const f4*)(a + (size_t)(i0 + ar) * 256 + ac);
  f4 pa1 = *(const f4*)(a + (size_t)(i0 + ar + 16) * 256 + ac);
  f4 pb0 = *(const f4*)(b + (size_t)br * Nb + j0 + bc);
  f4 pb1 = *(const f4*)(b + (size_t)(br + 32) * Nb + j0 + bc);
  for (int r4 = 0; r4 < 4; ++r4) {
    const int bs = r4 & 1;
#pragma unroll
    for (int m = 0; m < 4; ++m) {
      As[bs][ar][ac + m] = pa0[m];
      As[bs][ar + 16][ac + m] = pa1[m];
      Bs[bs][br][bc + m] = pb0[m];
      Bs[bs][br + 32][bc + m] = pb1[m];
    }
    if (r4 < 3) {
      int kk = (r4 + 1) * 64;
      pa0 = *(const f4*)(a + (size_t)(i0 + ar) * 256 + kk + ac);
      pa1 = *(const f4*)(a + (size_t)(i0 + ar + 16) * 256 + kk + ac);
      pb0 = *(const f4*)(b + (size_t)(kk + br) * Nb + j0 + bc);
      pb1 = *(const f4*)(b + (size_t)(kk + br + 32) * Nb + j0 + bc);
    }
    __syncthreads();
#pragma unroll 8
    for (int k = 0; k < 64; ++k) {
      float a0 = As[bs][ty * 2][k], a1 = As[bs][ty * 2 + 1][k];
      float b0 = Bs[bs][k][tx * 2], b1 = Bs[bs][k][tx * 2 + 1];
      acc[0][0] += a0 * b0; acc[0][1] += a0 * b1;
      acc[1][0] += a1 * b0; acc[1][1] += a1 * b1;
    }
  }
}

// ---------------- E,F from M; y0 exact fp32; B16 cast ----------------
__global__ __launch_bounds__(256) void k_ef(const float* __restrict__ M, const float* __restrict__ B,
                                            const float* __restrict__ C, const float* __restrict__ D,
                                            const float* __restrict__ x0, const float* __restrict__ u,
                                            float* __restrict__ E, float* __restrict__ F,
                                            _Float16* __restrict__ B16, float* __restrict__ out) {
  const int tid = threadIdx.x;
  int z = blockIdx.x >> 6;
  if (z >= 2) {
    if (blockIdx.x < 192) {  // y0
      int idx = (blockIdx.x - 128) * 256 + tid;
      int b = idx >> 7, col = idx & 127;
      const float* crow = C + (size_t)col * 256;
      const float* drow = D + (size_t)col * 128;
      const float* ur = u + (size_t)b * (TT * NU);
      float s = 0.f;
#pragma unroll 8
      for (int j = 0; j < 256; j += 4) {
        f4 cv = *(const f4*)(crow + j);
        f4 xv = *(const f4*)(x0 + j);
        s += cv[0] * xv[0] + cv[1] * xv[1] + cv[2] * xv[2] + cv[3] * xv[3];
      }
#pragma unroll 8
      for (int j = 0; j < 128; j += 4) {
        f4 dv = *(const f4*)(drow + j);
        f4 uv = *(const f4*)(ur + j);
        s += dv[0] * uv[0] + dv[1] * uv[1] + dv[2] * uv[2] + dv[3] * uv[3];
      }
      out[(size_t)b * (TT * NY) + col] = s;
    } else {  // B16 cast
      int i = (blockIdx.x - 192) * 1024 + tid;
      B16[i] = (_Float16)B[i];
      B16[i + 256] = (_Float16)B[i + 256];
      B16[i + 512] = (_Float16)B[i + 512];
      B16[i + 768] = (_Float16)B[i + 768];
    }
    return;
  }
  __shared__ float Ps[2][32][65], Qs[2][32][65];
  int tile = blockIdx.x & 63;
  int i0 = (tile >> 3) * 32, j0 = (tile & 7) * 32;
  const int ar = tid >> 4, ac = (tid & 15) * 4;
  const int tx = tid & 15, ty = tid >> 4;
  float acc[2][2] = {{0.f, 0.f}, {0.f, 0.f}};
  int np = (z == 0) ? 2 : 1;
  int rc = 0;
  for (int p = 0; p < np; ++p) {
    int po = (z == 0) ? p * 256 : 256;
    int qo = (z == 0) ? p * 256 : 0;
    f4 p0 = *(const f4*)(M + (size_t)(i0 + po + ar) * 512 + ac);
    f4 p1 = *(const f4*)(M + (size_t)(i0 + po + ar + 16) * 512 + ac);
    f4 q0 = *(const f4*)(M + (size_t)(j0 + qo + ar) * 512 + ac);
    f4 q1 = *(const f4*)(M + (size_t)(j0 + qo + ar + 16) * 512 + ac);
    for (int kk = 0; kk < 512; kk += 64) {
      const int bs = rc & 1;
      ++rc;
#pragma unroll
      for (int m = 0; m < 4; ++m) {
        Ps[bs][ar][ac + m] = p0[m];
        Ps[bs][ar + 16][ac + m] = p1[m];
        Qs[bs][ar][ac + m] = q0[m];
        Qs[bs][ar + 16][ac + m] = q1[m];
      }
      if (kk < 448) {
        int k2 = kk + 64;
        p0 = *(const f4*)(M + (size_t)(i0 + po + ar) * 512 + k2 + ac);
        p1 = *(const f4*)(M + (size_t)(i0 + po + ar + 16) * 512 + k2 + ac);
        q0 = *(const f4*)(M + (size_t)(j0 + qo + ar) * 512 + k2 + ac);
        q1 = *(const f4*)(M + (size_t)(j0 + qo + ar + 16) * 512 + k2 + ac);
      }
      __syncthreads();
#pragma unroll 8
      for (int k = 0; k < 64; ++k) {
        float a0 = Ps[bs][ty * 2][k], a1 = Ps[bs][ty * 2 + 1][k];
        float b0 = Qs[bs][tx * 2][k], b1 = Qs[bs][tx * 2 + 1][k];
        acc[0][0] += a0 * b0; acc[0][1] += a0 * b1;
        acc[1][0] += a1 * b0; acc[1][1] += a1 * b1;
      }
    }
  }
#pragma unroll
  for (int ii = 0; ii < 2; ++ii)
#pragma unroll
    for (int jj = 0; jj < 2; ++jj) {
      int i = i0 + ty * 2 + ii, j = j0 + tx * 2 + jj;
      if (z == 0) {
        float v = 0.5f * acc[ii][jj];
        if (i == j) v += 1e-9f;
        E[i * 256 + j] = v;
      } else {
        F[i * 256 + j] = acc[ii][jj];
      }
    }
}

// ---------------- NS init ----------------
__global__ __launch_bounds__(256) void k_ns0(const float* __restrict__ E,
                                             float* __restrict__ X, float* __restrict__ Y) {
  __shared__ float As[2][32][65];
  __shared__ float Bs[2][64][33];
  __shared__ float s1[256], red[256];
  const int tid = threadIdx.x;
  {
    float s = 0.f;
    const float* row = E + (size_t)tid * 256;
#pragma unroll 8
    for (int j = 0; j < 256; j += 4) {
      f4 e = *(const f4*)(row + j);
      s += e[0] + e[1] + e[2] + e[3];
    }
    s1[tid] = s; red[tid] = s * s;
  }
  __syncthreads();
  for (int o = 128; o > 0; o >>= 1) { if (tid < o) red[tid] += red[tid + o]; __syncthreads(); }
  float n1 = red[0];
  __syncthreads();
  {
    float s = 0.f;
    const float* row = E + (size_t)tid * 256;
#pragma unroll 8
    for (int j = 0; j < 256; j += 4) {
      f4 e = *(const f4*)(row + j);
      f4 vv = *(const f4*)(&s1[j]);
      s += e[0] * vv[0] + e[1] * vv[1] + e[2] * vv[2] + e[3] * vv[3];
    }
    red[tid] = s * s;
  }
  __syncthreads();
  for (int o = 128; o > 0; o >>= 1) { if (tid < o) red[tid] += red[tid + o]; __syncthreads(); }
  float c = sqrtf(n1 / red[0]);
  __syncthreads();
  if (blockIdx.x < 64) {
    int i0 = (blockIdx.x >> 3) * 32, j0 = (blockIdx.x & 7) * 32;
    float acc[2][2] = {{0.f, 0.f}, {0.f, 0.f}};
    mm_core(E, E, 256, i0, j0, tid, As, Bs, acc);
    int tx = tid & 15, ty = tid >> 4;
#pragma unroll
    for (int ii = 0; ii < 2; ++ii)
#pragma unroll
      for (int jj = 0; jj < 2; ++jj) {
        int i = i0 + ty * 2 + ii, j = j0 + tx * 2 + jj;
        Y[(size_t)i * 256 + j] = 2.f * c * E[(size_t)i * 256 + j] - c * c * acc[ii][jj];
      }
  } else {
    int idx = (blockIdx.x - 64) * 1024 + tid * 4;
    int i = idx >> 8, j = idx & 255;
    f4 e = *(const f4*)(E + idx);
    f4 v;
#pragma unroll
    for (int m = 0; m < 4; ++m) v[m] = ((j + m) == i ? 2.f * c : 0.f) - c * c * e[m];
    *(f4*)(X + idx) = v;
  }
}

// ---------------- multi-job fp32 GEMM ----------------
struct MMJob {
  const float* a; const float* b; const float* add;
  float* d32; _Float16* d16;
  int M, N, mode, blk0;
};

__global__ __launch_bounds__(256) void k_mm(MMJob j0, MMJob j1, MMJob j2, int njobs) {
  __shared__ float As[2][32][65];
  __shared__ float Bs[2][64][33];
  const int tid = threadIdx.x;
  int bid = blockIdx.x;
  MMJob jb = j0;
  if (njobs > 1 && bid >= j1.blk0) jb = j1;
  if (njobs > 2 && bid >= j2.blk0) jb = j2;
  int rel = bid - jb.blk0;
  int ntile = jb.N >> 5;
  int i0 = (rel / ntile) * 32, j0g = (rel % ntile) * 32;
  float acc[2][2] = {{0.f, 0.f}, {0.f, 0.f}};
  mm_core(jb.a, jb.b, jb.N, i0, j0g, tid, As, Bs, acc);
  int tx = tid & 15, ty = tid >> 4;
#pragma unroll
  for (int ii = 0; ii < 2; ++ii)
#pragma unroll
    for (int jj = 0; jj < 2; ++jj) {
      int i = i0 + ty * 2 + ii, j = j0g + tx * 2 + jj;
      size_t o = (size_t)i * jb.N + j;
      float v = acc[ii][jj];
      if (jb.mode == 1) v = 2.f * jb.a[(size_t)i * 256 + j] - v;
      else if (jb.add) v += jb.add[o];
      if (jb.d32) jb.d32[o] = v;
      if (jb.d16) jb.d16[o] = (_Float16)v;
    }
}

// ---------------- phase W: zero-init chunk increments w ----------------
__global__ __launch_bounds__(512, 2) void k_recW(const float* __restrict__ u,
                                                 const _Float16* __restrict__ A16,
                                                 const _Float16* __restrict__ B16,
                                                 float* __restrict__ w) {
  __shared__ __align__(16) char sm[24576];
  char* xb = sm;
  char* ub = sm + 16384;
  const int tid = threadIdx.x, lane = tid & 63, wv = tid >> 6;
  const int g = lane >> 4, lr = lane & 15;
  const int chunk = blockIdx.x >> 3, btile = blockIdx.x & 7;
  const int b0 = btile * 16, t0 = chunk * LCH, nt0 = wv * 2;

  h8 Ar[2][8], Bf[2][4];
#pragma unroll
  for (int n2 = 0; n2 < 2; ++n2) {
#pragma unroll
    for (int kf = 0; kf < 8; ++kf) {
      Ar[n2][kf] = *(const h8*)(A16 + (size_t)((nt0 + n2) * 16 + lr) * NX + kf * 32 + g * 8);
      PIN(Ar[n2][kf]);
    }
#pragma unroll
    for (int kf = 0; kf < 4; ++kf) {
      Bf[n2][kf] = *(const h8*)(B16 + (size_t)((nt0 + n2) * 16 + lr) * NU + kf * 32 + g * 8);
      PIN(Bf[n2][kf]);
    }
  }
  const int urow = tid >> 5, uuc = tid & 31;
  const float* ubase = u + (size_t)(b0 + urow) * (TT * NU) + uuc * 4;
  const int uoff = swz256(urow, uuc * 8);
  {
    f4 r0 = *(const f4*)(ubase + (size_t)t0 * NU);
    *(h4*)(ub + uoff) = h4cvt(r0);
  }
  f4 urA = *(const f4*)(ubase + (size_t)(t0 + 1) * NU);
  f4 urB = *(const f4*)(ubase + (size_t)(t0 + 2 < TT ? t0 + 2 : TT - 1) * NU);
  h8 af[8];
#pragma unroll
  for (int kf = 0; kf < 8; ++kf) af[kf] = h8zero();
  __syncthreads();

  f4 z4 = {0.f, 0.f, 0.f, 0.f};
  f4 xacc[2];
#pragma unroll 2
  for (int i = 0; i < LCH; ++i) {
    const int p = i & 1;
    if (i < LCH - 1) {
      int nt = t0 + i + 3;
      if (nt > TT - 1) nt = TT - 1;
      if (p == 0) {
        *(h4*)(ub + 4096 + uoff) = h4cvt(urA);
        urA = *(const f4*)(ubase + (size_t)nt * NU);
      } else {
        *(h4*)(ub + uoff) = h4cvt(urB);
        urB = *(const f4*)(ubase + (size_t)nt * NU);
      }
    }
    h8 uf[4];
#pragma unroll
    for (int kf = 0; kf < 4; ++kf)
      uf[kf] = *(const h8*)(ub + p * 4096 + swz256(lr, kf * 64 + g * 16));
    __builtin_amdgcn_s_setprio(1);
    xacc[0] = z4; xacc[1] = z4;
#pragma unroll
    for (int kf = 0; kf < 8; ++kf) {
      xacc[0] = mfma16(Ar[0][kf], af[kf], xacc[0]);
      xacc[1] = mfma16(Ar[1][kf], af[kf], xacc[1]);
    }
#pragma unroll
    for (int kf = 0; kf < 4; ++kf) {
      xacc[0] = mfma16(Bf[0][kf], uf[kf], xacc[0]);
      xacc[1] = mfma16(Bf[1][kf], uf[kf], xacc[1]);
    }
    __builtin_amdgcn_s_setprio(0);
    if (i < LCH - 1) {
#pragma unroll
      for (int n2 = 0; n2 < 2; ++n2)
        *(h4*)(xb + (p ^ 1) * 8192 + lr * 512 + ((((nt0 + n2) * 32) + g * 8) ^ ((lr & 7) << 4))) =
            h4cvt(xacc[n2]);
      LBAR();
#pragma unroll
      for (int kf = 0; kf < 8; ++kf)
        af[kf] = *(const h8*)(xb + (p ^ 1) * 8192 + lr * 512 + ((kf * 64 + g * 16) ^ ((lr & 7) << 4)));
    }
  }
#pragma unroll
  for (int n2 = 0; n2 < 2; ++n2)
    *(f4*)(w + ((size_t)chunk * BSZ + b0 + lr) * NX + (nt0 + n2) * 16 + g * 4) = xacc[n2];
}

// ---------------- phase B: sequential chunk combine ----------------
__global__ __launch_bounds__(512, 2) void k_phB(const float* __restrict__ x0,
                                                const float* __restrict__ w,
                                                const _Float16* __restrict__ Ah16,
                                                float* __restrict__ xs) {
  __shared__ __align__(16) char xb[16384];
  const int tid = threadIdx.x, lane = tid & 63, wv = tid >> 6;
  const int g = lane >> 4, lr = lane & 15;
  const int b0 = blockIdx.x * 16, nt0 = wv * 2;
  h8 Ar[2][8];
#pragma unroll
  for (int n2 = 0; n2 < 2; ++n2)
#pragma unroll
    for (int kf = 0; kf < 8; ++kf) {
      Ar[n2][kf] = *(const h8*)(Ah16 + (size_t)((nt0 + n2) * 16 + lr) * NX + kf * 32 + g * 8);
      PIN(Ar[n2][kf]);
    }
  for (int s = 0; s < 8; ++s) {
    int e = tid + s * 512;
    int row = e >> 8, c = e & 255;
    xs[(size_t)(b0 + row) * NX + c] = x0[c];
  }
  h8 af[8];
#pragma unroll
  for (int kf = 0; kf < 8; ++kf) {
    const float* sp = x0 + kf * 32 + g * 8;
    af[kf] = cvt8(*(const f4*)sp, *(const f4*)(sp + 4));
  }
  f4 wl[2];
#pragma unroll
  for (int n2 = 0; n2 < 2; ++n2)
    wl[n2] = *(const f4*)(w + ((size_t)0 * BSZ + b0 + lr) * NX + (nt0 + n2) * 16 + g * 4);
  f4 z4 = {0.f, 0.f, 0.f, 0.f};
  for (int k = 0; k < KCH - 1; ++k) {
    const int p = k & 1;
    f4 wn[2] = {z4, z4};
    if (k < KCH - 2) {
#pragma unroll
      for (int n2 = 0; n2 < 2; ++n2)
        wn[n2] = *(const f4*)(w + ((size_t)(k + 1) * BSZ + b0 + lr) * NX + (nt0 + n2) * 16 + g * 4);
    }
    f4 acc[2] = {z4, z4};
#pragma unroll
    for (int kf = 0; kf < 8; ++kf) {
      acc[0] = mfma16(Ar[0][kf], af[kf], acc[0]);
      acc[1] = mfma16(Ar[1][kf], af[kf], acc[1]);
    }
#pragma unroll
    for (int n2 = 0; n2 < 2; ++n2) {
      acc[n2] += wl[n2];
      *(f4*)(xs + ((size_t)(k + 1) * BSZ + b0 + lr) * NX + (nt0 + n2) * 16 + g * 4) = acc[n2];
    }
    if (k < KCH - 2) {
#pragma unroll
      for (int n2 = 0; n2 < 2; ++n2)
        *(h4*)(xb + (p ^ 1) * 8192 + lr * 512 + ((((nt0 + n2) * 32) + g * 8) ^ ((lr & 7) << 4))) =
            h4cvt(acc[n2]);
      LBAR();
#pragma unroll
      for (int kf = 0; kf < 8; ++kf)
        af[kf] = *(const h8*)(xb + (p ^ 1) * 8192 + lr * 512 + ((kf * 64 + g * 16) ^ ((lr & 7) << 4)));
    }
#pragma unroll
    for (int n2 = 0; n2 < 2; ++n2) wl[n2] = wn[n2];
  }
}

// ---------------- phase Y: true-init recurrence, emits exact y (LDS u path) ----------------
__global__ __launch_bounds__(512, 2) void k_recY(const float* __restrict__ u,
                                                 const _Float16* __restrict__ A16,
                                                 const _Float16* __restrict__ B16,
                                                 const _Float16* __restrict__ CA16,
                                                 const _Float16* __restrict__ CBD16,
                                                 const float* __restrict__ xs,
                                                 float* __restrict__ out) {
  __shared__ __align__(16) char sm[24576];
  char* xb = sm;
  char* ub = sm + 16384;
  const int tid = threadIdx.x, lane = tid & 63, wv = tid >> 6;
  const int g = lane >> 4, lr = lane & 15;
  const int chunk = blockIdx.x >> 3, btile = blockIdx.x & 7;
  const int b0 = btile * 16, t0 = chunk * LCH, nt0 = wv * 2;

  h8 Ar[2][8], Bf[2][4], Cf[8], Df[4];
#pragma unroll
  for (int n2 = 0; n2 < 2; ++n2) {
#pragma unroll
    for (int kf = 0; kf < 8; ++kf) {
      Ar[n2][kf] = *(const h8*)(A16 + (size_t)((nt0 + n2) * 16 + lr) * NX + kf * 32 + g * 8);
      PIN(Ar[n2][kf]);
    }
#pragma unroll
    for (int kf = 0; kf < 4; ++kf) {
      Bf[n2][kf] = *(const h8*)(B16 + (size_t)((nt0 + n2) * 16 + lr) * NU + kf * 32 + g * 8);
      PIN(Bf[n2][kf]);
    }
  }
#pragma unroll
  for (int kf = 0; kf < 8; ++kf) {
    Cf[kf] = *(const h8*)(CA16 + (size_t)(wv * 16 + lr) * NX + kf * 32 + g * 8);
    PIN(Cf[kf]);
  }
#pragma unroll
  for (int kf = 0; kf < 4; ++kf) {
    Df[kf] = *(const h8*)(CBD16 + (size_t)(wv * 16 + lr) * NU + kf * 32 + g * 8);
    PIN(Df[kf]);
  }
  h8 af[8];
#pragma unroll
  for (int kf = 0; kf < 8; ++kf) {
    const float* sp = xs + ((size_t)chunk * BSZ + b0 + lr) * NX + kf * 32 + g * 8;
    af[kf] = cvt8(*(const f4*)sp, *(const f4*)(sp + 4));
  }
  const int urow = tid >> 5, uuc = tid & 31;
  const float* ubase = u + (size_t)(b0 + urow) * (TT * NU) + uuc * 4;
  const int uoff = swz256(urow, uuc * 8);
  float* obase = out + (size_t)(b0 + lr) * (TT * NY) + wv * 16 + g * 4;
  {
    f4 r0 = *(const f4*)(ubase + (size_t)t0 * NU);
    *(h4*)(ub + uoff) = h4cvt(r0);
  }
  f4 urA = *(const f4*)(ubase + (size_t)(t0 + 1) * NU);
  f4 urB = *(const f4*)(ubase + (size_t)(t0 + 2 < TT ? t0 + 2 : TT - 1) * NU);
  __syncthreads();

  f4 z4 = {0.f, 0.f, 0.f, 0.f};
#pragma unroll 2
  for (int i = 0; i < LCH; ++i) {
    const int p = i & 1;
    if (i < LCH - 1) {
      int nt = t0 + i + 3;
      if (nt > TT - 1) nt = TT - 1;
      if (p == 0) {
        *(h4*)(ub + 4096 + uoff) = h4cvt(urA);
        urA = *(const f4*)(ubase + (size_t)nt * NU);
      } else {
        *(h4*)(ub + uoff) = h4cvt(urB);
        urB = *(const f4*)(ubase + (size_t)nt * NU);
      }
    }
    h8 uf[4];
#pragma unroll
    for (int kf = 0; kf < 4; ++kf)
      uf[kf] = *(const h8*)(ub + p * 4096 + swz256(lr, kf * 64 + g * 16));
    // x-update first (shortens pre-barrier critical path)
    if (i < LCH - 1) {
      __builtin_amdgcn_s_setprio(1);
      f4 xacc[2] = {z4, z4};
#pragma unroll
      for (int kf = 0; kf < 8; ++kf) {
        xacc[0] = mfma16(Ar[0][kf], af[kf], xacc[0]);
        xacc[1] = mfma16(Ar[1][kf], af[kf], xacc[1]);
      }
#pragma unroll
      for (int kf = 0; kf < 4; ++kf) {
        xacc[0] = mfma16(Bf[0][kf], uf[kf], xacc[0]);
        xacc[1] = mfma16(Bf[1][kf], uf[kf], xacc[1]);
      }
      __builtin_amdgcn_s_setprio(0);
#pragma unroll
      for (int n2 = 0; n2 < 2; ++n2)
        *(h4*)(xb + (p ^ 1) * 8192 + lr * 512 + ((((nt0 + n2) * 32) + g * 8) ^ ((lr & 7) << 4))) =
            h4cvt(xacc[n2]);
    }
    __builtin_amdgcn_s_setprio(1);
    f4 yacc = z4;
#pragma unroll
    for (int kf = 0; kf < 8; ++kf) yacc = mfma16(Cf[kf], af[kf], yacc);
#pragma unroll
    for (int kf = 0; kf < 4; ++kf) yacc = mfma16(Df[kf], uf[kf], yacc);
    __builtin_amdgcn_s_setprio(0);
    int t = t0 + i + 1;
    if (t < TT) *(f4*)(obase + (size_t)t * NY) = yacc;
    if (i < LCH - 1) {
      LBAR();
#pragma unroll
      for (int kf = 0; kf < 8; ++kf)
        af[kf] = *(const h8*)(xb + (p ^ 1) * 8192 + lr * 512 + ((kf * 64 + g * 16) ^ ((lr & 7) << 4)));
    }
  }
}

extern "C" void kernel_launch(void* const* d_in, const int* in_sizes, int n_in,
                              void* d_out, int out_size, void* d_ws, size_t ws_size,
                              hipStream_t stream) {
  const float* u  = (const float*)d_in[0];
  const float* M  = (const float*)d_in[1];
  const float* B  = (const float*)d_in[2];
  const float* C  = (const float*)d_in[3];
  const float* D  = (const float*)d_in[4];
  const float* x0 = (const float*)d_in[5];
  float* out = (float*)d_out;
  char* ws = (char*)d_ws;

  float* E    = (float*)(ws + 0L);
  float* F    = (float*)(ws + 256L * 1024);
  float* X1   = (float*)(ws + 512L * 1024);
  float* Y1   = (float*)(ws + 768L * 1024);
  float* X2   = (float*)(ws + 1024L * 1024);
  float* Y2   = (float*)(ws + 1280L * 1024);
  float* Amat = (float*)(ws + 1536L * 1024);
  float* P2   = (float*)(ws + 1792L * 1024);
  float* P4   = (float*)(ws + 2048L * 1024);
  float* P8   = (float*)(ws + 2304L * 1024);
  float* P16  = (float*)(ws + 2560L * 1024);
  _Float16* A16   = (_Float16*)(ws + 2816L * 1024);
  _Float16* Ah16  = (_Float16*)(ws + 2944L * 1024);
  _Float16* B16   = (_Float16*)(ws + 3072L * 1024);
  _Float16* CA16  = (_Float16*)(ws + 3136L * 1024);
  _Float16* CBD16 = (_Float16*)(ws + 3200L * 1024);
  float* wbuf = (float*)(ws + 9408L * 1024);           // 8 MB
  float* xs   = (float*)(ws + 17600L * 1024);          // 8 MB

  MMJob nil = {nullptr, nullptr, nullptr, nullptr, nullptr, 0, 0, 0, 0};

  k_ef<<<224, 256, 0, stream>>>(M, B, C, D, x0, u, E, F, B16, out);
  k_ns0<<<128, 256, 0, stream>>>(E, X1, Y1);
  float *Xc = X1, *Yc = Y1, *Xn = X2, *Yn = Y2;
  for (int it = 0; it < 6; ++it) {
    MMJob jx = {Xc, Yc, nullptr, Xn, nullptr, 256, 256, 1, 0};
    MMJob jy = {Yc, Yc, nullptr, Yn, nullptr, 256, 256, 1, 64};
    k_mm<<<128, 256, 0, stream>>>(jx, jy, nil, 2);
    float* t1 = Xc; Xc = Xn; Xn = t1;
    float* t2 = Yc; Yc = Yn; Yn = t2;
  }
  {  // A = E^-1 F
    MMJob ja = {Xc, F, nullptr, Amat, A16, 256, 256, 0, 0};
    k_mm<<<64, 256, 0, stream>>>(ja, nil, nil, 1);
  }
  {  // A^2 ; CA -> CA16 ; CBD = C B + D -> CBD16
    MMJob j0 = {Amat, Amat, nullptr, P2, nullptr, 256, 256, 0, 0};
    MMJob j1 = {C, Amat, nullptr, nullptr, CA16, 128, 256, 0, 64};
    MMJob j2 = {C, B, D, nullptr, CBD16, 128, 128, 0, 96};
    k_mm<<<112, 256, 0, stream>>>(j0, j1, j2, 3);
  }
  {  // A^4
    MMJob j0 = {P2, P2, nullptr, P4, nullptr, 256, 256, 0, 0};
    k_mm<<<64, 256, 0, stream>>>(j0, nil, nil, 1);
  }
  {  // A^8
    MMJob j0 = {P4, P4, nullptr, P8, nullptr, 256, 256, 0, 0};
    k_mm<<<64, 256, 0, stream>>>(j0, nil, nil, 1);
  }
  {  // A^16
    MMJob j0 = {P8, P8, nullptr, P16, nullptr, 256, 256, 0, 0};
    k_mm<<<64, 256, 0, stream>>>(j0, nil, nil, 1);
  }
  {  // A^32 -> Ah16
    MMJob j0 = {P16, P16, nullptr, nullptr, Ah16, 256, 256, 0, 0};
    k_mm<<<64, 256, 0, stream>>>(j0, nil, nil, 1);
  }

  k_recW<<<512, 512, 0, stream>>>(u, A16, B16, wbuf);
  k_phB<<<8, 512, 0, stream>>>(x0, wbuf, Ah16, xs);
  k_recY<<<512, 512, 0, stream>>>(u, A16, B16, CA16, CBD16, xs, out);
}

// Round 16
// 347.512 us; speedup vs baseline: 1.2053x; 1.0005x over previous
//
#include <hip/hip_runtime.h>

#define NX 256
#define NU 128
#define NY 128
#define BSZ 128
#define TT 2048
#define LCH 32
#define KCH 64

typedef _Float16 h8 __attribute__((ext_vector_type(8)));
typedef _Float16 h4 __attribute__((ext_vector_type(4)));
typedef float f4 __attribute__((ext_vector_type(4)));

__device__ __forceinline__ f4 mfma16(h8 a, h8 b, f4 c) {
  return __builtin_amdgcn_mfma_f32_16x16x32_f16(a, b, c, 0, 0, 0);
}
#define PIN(x) asm volatile("" : "+v"(x))
#define LBAR() asm volatile("s_waitcnt lgkmcnt(0)\n\ts_barrier" ::: "memory")

__device__ __forceinline__ int swz256(int row, int bc) { return row * 256 + (bc ^ ((row & 7) << 4)); }
// x-exchange swizzle: phys = canon ^ ((row&7)<<4) ^ ((canon&16)<<1)  (bijective involution)
__device__ __forceinline__ int xwSwz(int row, int canon) {
  return row * 512 + (canon ^ ((row & 7) << 4) ^ ((canon & 16) << 1));
}

__device__ __forceinline__ h8 cvt8(f4 lo, f4 hi) {
  h8 h;
#pragma unroll
  for (int j = 0; j < 4; ++j) { h[j] = (_Float16)lo[j]; h[j + 4] = (_Float16)hi[j]; }
  return h;
}
__device__ __forceinline__ h4 h4cvt(f4 v) {
  h4 h;
#pragma unroll
  for (int j = 0; j < 4; ++j) h[j] = (_Float16)v[j];
  return h;
}
__device__ __forceinline__ h8 h8zero() {
  h8 h;
#pragma unroll
  for (int j = 0; j < 8; ++j) h[j] = (_Float16)0.0f;
  return h;
}

// ---- fp32 GEMM core: 32x32 tile, K=256, lda=256, dbuf K=64 rounds + reg prefetch ----
__device__ __forceinline__ void mm_core(const float* __restrict__ a, const float* __restrict__ b,
                                        int Nb, int i0, int j0, int tid,
                                        float (*As)[32][65], float (*Bs)[64][33],
                                        float acc[2][2]) {
  const int ar = tid >> 4, ac = (tid & 15) * 4;
  const int br = tid >> 3, bc = (tid & 7) * 4;
  const int tx = tid & 15, ty = tid >> 4;
  f4 pa0 = *(const f4*)(a + (size_t)(i0 + ar) * 256 + ac);
  f4 pa1 = *(const f4*)(a + (size_t)(i0 + ar + 16) * 256 + ac);
  f4 pb0 = *(const f4*)(b + (size_t)br * Nb + j0 + bc);
  f4 pb1 = *(const f4*)(b + (size_t)(br + 32) * Nb + j0 + bc);
  for (int r4 = 0; r4 < 4; ++r4) {
    const int bs = r4 & 1;
#pragma unroll
    for (int m = 0; m < 4; ++m) {
      As[bs][ar][ac + m] = pa0[m];
      As[bs][ar + 16][ac + m] = pa1[m];
      Bs[bs][br][bc + m] = pb0[m];
      Bs[bs][br + 32][bc + m] = pb1[m];
    }
    if (r4 < 3) {
      int kk = (r4 + 1) * 64;
      pa0 = *(const f4*)(a + (size_t)(i0 + ar) * 256 + kk + ac);
      pa1 = *(const f4*)(a + (size_t)(i0 + ar + 16) * 256 + kk + ac);
      pb0 = *(const f4*)(b + (size_t)(kk + br) * Nb + j0 + bc);
      pb1 = *(const f4*)(b + (size_t)(kk + br + 32) * Nb + j0 + bc);
    }
    __syncthreads();
#pragma unroll 8
    for (int k = 0; k < 64; ++k) {
      float a0 = As[bs][ty * 2][k], a1 = As[bs][ty * 2 + 1][k];
      float b0 = Bs[bs][k][tx * 2], b1 = Bs[bs][k][tx * 2 + 1];
      acc[0][0] += a0 * b0; acc[0][1] += a0 * b1;
      acc[1][0] += a1 * b0; acc[1][1] += a1 * b1;
    }
  }
}

// ---------------- E,F from M; y0 exact fp32; B16 cast ----------------
__global__ __launch_bounds__(256) void k_ef(const float* __restrict__ M, const float* __restrict__ B,
                                            const float* __restrict__ C, const float* __restrict__ D,
                                            const float* __restrict__ x0, const float* __restrict__ u,
                                            float* __restrict__ E, float* __restrict__ F,
                                            _Float16* __restrict__ B16, float* __restrict__ out) {
  const int tid = threadIdx.x;
  int z = blockIdx.x >> 6;
  if (z >= 2) {
    if (blockIdx.x < 192) {  // y0
      int idx = (blockIdx.x - 128) * 256 + tid;
      int b = idx >> 7, col = idx & 127;
      const float* crow = C + (size_t)col * 256;
      const float* drow = D + (size_t)col * 128;
      const float* ur = u + (size_t)b * (TT * NU);
      float s = 0.f;
#pragma unroll 8
      for (int j = 0; j < 256; j += 4) {
        f4 cv = *(const f4*)(crow + j);
        f4 xv = *(const f4*)(x0 + j);
        s += cv[0] * xv[0] + cv[1] * xv[1] + cv[2] * xv[2] + cv[3] * xv[3];
      }
#pragma unroll 8
      for (int j = 0; j < 128; j += 4) {
        f4 dv = *(const f4*)(drow + j);
        f4 uv = *(const f4*)(ur + j);
        s += dv[0] * uv[0] + dv[1] * uv[1] + dv[2] * uv[2] + dv[3] * uv[3];
      }
      out[(size_t)b * (TT * NY) + col] = s;
    } else {  // B16 cast
      int i = (blockIdx.x - 192) * 1024 + tid;
      B16[i] = (_Float16)B[i];
      B16[i + 256] = (_Float16)B[i + 256];
      B16[i + 512] = (_Float16)B[i + 512];
      B16[i + 768] = (_Float16)B[i + 768];
    }
    return;
  }
  __shared__ float Ps[2][32][65], Qs[2][32][65];
  int tile = blockIdx.x & 63;
  int i0 = (tile >> 3) * 32, j0 = (tile & 7) * 32;
  const int ar = tid >> 4, ac = (tid & 15) * 4;
  const int tx = tid & 15, ty = tid >> 4;
  float acc[2][2] = {{0.f, 0.f}, {0.f, 0.f}};
  int np = (z == 0) ? 2 : 1;
  int rc = 0;
  for (int p = 0; p < np; ++p) {
    int po = (z == 0) ? p * 256 : 256;
    int qo = (z == 0) ? p * 256 : 0;
    f4 p0 = *(const f4*)(M + (size_t)(i0 + po + ar) * 512 + ac);
    f4 p1 = *(const f4*)(M + (size_t)(i0 + po + ar + 16) * 512 + ac);
    f4 q0 = *(const f4*)(M + (size_t)(j0 + qo + ar) * 512 + ac);
    f4 q1 = *(const f4*)(M + (size_t)(j0 + qo + ar + 16) * 512 + ac);
    for (int kk = 0; kk < 512; kk += 64) {
      const int bs = rc & 1;
      ++rc;
#pragma unroll
      for (int m = 0; m < 4; ++m) {
        Ps[bs][ar][ac + m] = p0[m];
        Ps[bs][ar + 16][ac + m] = p1[m];
        Qs[bs][ar][ac + m] = q0[m];
        Qs[bs][ar + 16][ac + m] = q1[m];
      }
      if (kk < 448) {
        int k2 = kk + 64;
        p0 = *(const f4*)(M + (size_t)(i0 + po + ar) * 512 + k2 + ac);
        p1 = *(const f4*)(M + (size_t)(i0 + po + ar + 16) * 512 + k2 + ac);
        q0 = *(const f4*)(M + (size_t)(j0 + qo + ar) * 512 + k2 + ac);
        q1 = *(const f4*)(M + (size_t)(j0 + qo + ar + 16) * 512 + k2 + ac);
      }
      __syncthreads();
#pragma unroll 8
      for (int k = 0; k < 64; ++k) {
        float a0 = Ps[bs][ty * 2][k], a1 = Ps[bs][ty * 2 + 1][k];
        float b0 = Qs[bs][tx * 2][k], b1 = Qs[bs][tx * 2 + 1][k];
        acc[0][0] += a0 * b0; acc[0][1] += a0 * b1;
        acc[1][0] += a1 * b0; acc[1][1] += a1 * b1;
      }
    }
  }
#pragma unroll
  for (int ii = 0; ii < 2; ++ii)
#pragma unroll
    for (int jj = 0; jj < 2; ++jj) {
      int i = i0 + ty * 2 + ii, j = j0 + tx * 2 + jj;
      if (z == 0) {
        float v = 0.5f * acc[ii][jj];
        if (i == j) v += 1e-9f;
        E[i * 256 + j] = v;
      } else {
        F[i * 256 + j] = acc[ii][jj];
      }
    }
}

// ---------------- NS init ----------------
__global__ __launch_bounds__(256) void k_ns0(const float* __restrict__ E,
                                             float* __restrict__ X, float* __restrict__ Y) {
  __shared__ float As[2][32][65];
  __shared__ float Bs[2][64][33];
  __shared__ float s1[256], red[256];
  const int tid = threadIdx.x;
  {
    float s = 0.f;
    const float* row = E + (size_t)tid * 256;
#pragma unroll 8
    for (int j = 0; j < 256; j += 4) {
      f4 e = *(const f4*)(row + j);
      s += e[0] + e[1] + e[2] + e[3];
    }
    s1[tid] = s; red[tid] = s * s;
  }
  __syncthreads();
  for (int o = 128; o > 0; o >>= 1) { if (tid < o) red[tid] += red[tid + o]; __syncthreads(); }
  float n1 = red[0];
  __syncthreads();
  {
    float s = 0.f;
    const float* row = E + (size_t)tid * 256;
#pragma unroll 8
    for (int j = 0; j < 256; j += 4) {
      f4 e = *(const f4*)(row + j);
      f4 vv = *(const f4*)(&s1[j]);
      s += e[0] * vv[0] + e[1] * vv[1] + e[2] * vv[2] + e[3] * vv[3];
    }
    red[tid] = s * s;
  }
  __syncthreads();
  for (int o = 128; o > 0; o >>= 1) { if (tid < o) red[tid] += red[tid + o]; __syncthreads(); }
  float c = sqrtf(n1 / red[0]);
  __syncthreads();
  if (blockIdx.x < 64) {
    int i0 = (blockIdx.x >> 3) * 32, j0 = (blockIdx.x & 7) * 32;
    float acc[2][2] = {{0.f, 0.f}, {0.f, 0.f}};
    mm_core(E, E, 256, i0, j0, tid, As, Bs, acc);
    int tx = tid & 15, ty = tid >> 4;
#pragma unroll
    for (int ii = 0; ii < 2; ++ii)
#pragma unroll
      for (int jj = 0; jj < 2; ++jj) {
        int i = i0 + ty * 2 + ii, j = j0 + tx * 2 + jj;
        Y[(size_t)i * 256 + j] = 2.f * c * E[(size_t)i * 256 + j] - c * c * acc[ii][jj];
      }
  } else {
    int idx = (blockIdx.x - 64) * 1024 + tid * 4;
    int i = idx >> 8, j = idx & 255;
    f4 e = *(const f4*)(E + idx);
    f4 v;
#pragma unroll
    for (int m = 0; m < 4; ++m) v[m] = ((j + m) == i ? 2.f * c : 0.f) - c * c * e[m];
    *(f4*)(X + idx) = v;
  }
}

// ---------------- multi-job fp32 GEMM ----------------
struct MMJob {
  const float* a; const float* b; const float* add;
  float* d32; _Float16* d16;
  int M, N, mode, blk0;
};

__global__ __launch_bounds__(256) void k_mm(MMJob j0, MMJob j1, MMJob j2, int njobs) {
  __shared__ float As[2][32][65];
  __shared__ float Bs[2][64][33];
  const int tid = threadIdx.x;
  int bid = blockIdx.x;
  MMJob jb = j0;
  if (njobs > 1 && bid >= j1.blk0) jb = j1;
  if (njobs > 2 && bid >= j2.blk0) jb = j2;
  int rel = bid - jb.blk0;
  int ntile = jb.N >> 5;
  int i0 = (rel / ntile) * 32, j0g = (rel % ntile) * 32;
  float acc[2][2] = {{0.f, 0.f}, {0.f, 0.f}};
  mm_core(jb.a, jb.b, jb.N, i0, j0g, tid, As, Bs, acc);
  int tx = tid & 15, ty = tid >> 4;
#pragma unroll
  for (int ii = 0; ii < 2; ++ii)
#pragma unroll
    for (int jj = 0; jj < 2; ++jj) {
      int i = i0 + ty * 2 + ii, j = j0g + tx * 2 + jj;
      size_t o = (size_t)i * jb.N + j;
      float v = acc[ii][jj];
      if (jb.mode == 1) v = 2.f * jb.a[(size_t)i * 256 + j] - v;
      else if (jb.add) v += jb.add[o];
      if (jb.d32) jb.d32[o] = v;
      if (jb.d16) jb.d16[o] = (_Float16)v;
    }
}

// ---------------- phase W: zero-init chunk increments w ----------------
__global__ __launch_bounds__(512, 2) void k_recW(const float* __restrict__ u,
                                                 const _Float16* __restrict__ A16,
                                                 const _Float16* __restrict__ B16,
                                                 float* __restrict__ w) {
  __shared__ __align__(16) char sm[24576];
  char* xb = sm;
  char* ub = sm + 16384;
  const int tid = threadIdx.x, lane = tid & 63, wv = tid >> 6;
  const int g = lane >> 4, lr = lane & 15;
  const int chunk = blockIdx.x >> 3, btile = blockIdx.x & 7;
  const int b0 = btile * 16, t0 = chunk * LCH, nt0 = wv * 2;

  h8 Ar[2][8], Bf[2][4];
#pragma unroll
  for (int n2 = 0; n2 < 2; ++n2) {
#pragma unroll
    for (int kf = 0; kf < 8; ++kf) {
      Ar[n2][kf] = *(const h8*)(A16 + (size_t)((nt0 + n2) * 16 + lr) * NX + kf * 32 + g * 8);
      PIN(Ar[n2][kf]);
    }
#pragma unroll
    for (int kf = 0; kf < 4; ++kf) {
      Bf[n2][kf] = *(const h8*)(B16 + (size_t)((nt0 + n2) * 16 + lr) * NU + kf * 32 + g * 8);
      PIN(Bf[n2][kf]);
    }
  }
  const int urow = tid >> 5, uuc = tid & 31;
  const float* ubase = u + (size_t)(b0 + urow) * (TT * NU) + uuc * 4;
  const int uoff = swz256(urow, uuc * 8);
  {
    f4 r0 = *(const f4*)(ubase + (size_t)t0 * NU);
    *(h4*)(ub + uoff) = h4cvt(r0);
  }
  f4 urA = *(const f4*)(ubase + (size_t)(t0 + 1) * NU);
  f4 urB = *(const f4*)(ubase + (size_t)(t0 + 2 < TT ? t0 + 2 : TT - 1) * NU);
  h8 af[8];
#pragma unroll
  for (int kf = 0; kf < 8; ++kf) af[kf] = h8zero();
  __syncthreads();

  f4 z4 = {0.f, 0.f, 0.f, 0.f};
  f4 xacc[2];
#pragma unroll 2
  for (int i = 0; i < LCH; ++i) {
    const int p = i & 1;
    if (i < LCH - 1) {
      int nt = t0 + i + 3;
      if (nt > TT - 1) nt = TT - 1;
      if (p == 0) {
        *(h4*)(ub + 4096 + uoff) = h4cvt(urA);
        urA = *(const f4*)(ubase + (size_t)nt * NU);
      } else {
        *(h4*)(ub + uoff) = h4cvt(urB);
        urB = *(const f4*)(ubase + (size_t)nt * NU);
      }
    }
    h8 uf[4];
#pragma unroll
    for (int kf = 0; kf < 4; ++kf)
      uf[kf] = *(const h8*)(ub + p * 4096 + swz256(lr, kf * 64 + g * 16));
    __builtin_amdgcn_s_setprio(1);
    xacc[0] = z4; xacc[1] = z4;
#pragma unroll
    for (int kf = 0; kf < 8; ++kf) {
      xacc[0] = mfma16(Ar[0][kf], af[kf], xacc[0]);
      xacc[1] = mfma16(Ar[1][kf], af[kf], xacc[1]);
    }
#pragma unroll
    for (int kf = 0; kf < 4; ++kf) {
      xacc[0] = mfma16(Bf[0][kf], uf[kf], xacc[0]);
      xacc[1] = mfma16(Bf[1][kf], uf[kf], xacc[1]);
    }
    __builtin_amdgcn_s_setprio(0);
    if (i < LCH - 1) {
#pragma unroll
      for (int n2 = 0; n2 < 2; ++n2)
        *(h4*)(xb + (p ^ 1) * 8192 + xwSwz(lr, (nt0 + n2) * 32 + g * 8)) = h4cvt(xacc[n2]);
      LBAR();
#pragma unroll
      for (int kf = 0; kf < 8; ++kf)
        af[kf] = *(const h8*)(xb + (p ^ 1) * 8192 + xwSwz(lr, kf * 64 + g * 16));
    }
  }
#pragma unroll
  for (int n2 = 0; n2 < 2; ++n2)
    *(f4*)(w + ((size_t)chunk * BSZ + b0 + lr) * NX + (nt0 + n2) * 16 + g * 4) = xacc[n2];
}

// ---------------- phase B: sequential chunk combine ----------------
__global__ __launch_bounds__(512, 2) void k_phB(const float* __restrict__ x0,
                                                const float* __restrict__ w,
                                                const _Float16* __restrict__ Ah16,
                                                float* __restrict__ xs) {
  __shared__ __align__(16) char xb[16384];
  const int tid = threadIdx.x, lane = tid & 63, wv = tid >> 6;
  const int g = lane >> 4, lr = lane & 15;
  const int b0 = blockIdx.x * 16, nt0 = wv * 2;
  h8 Ar[2][8];
#pragma unroll
  for (int n2 = 0; n2 < 2; ++n2)
#pragma unroll
    for (int kf = 0; kf < 8; ++kf) {
      Ar[n2][kf] = *(const h8*)(Ah16 + (size_t)((nt0 + n2) * 16 + lr) * NX + kf * 32 + g * 8);
      PIN(Ar[n2][kf]);
    }
  for (int s = 0; s < 8; ++s) {
    int e = tid + s * 512;
    int row = e >> 8, c = e & 255;
    xs[(size_t)(b0 + row) * NX + c] = x0[c];
  }
  h8 af[8];
#pragma unroll
  for (int kf = 0; kf < 8; ++kf) {
    const float* sp = x0 + kf * 32 + g * 8;
    af[kf] = cvt8(*(const f4*)sp, *(const f4*)(sp + 4));
  }
  f4 wl[2];
#pragma unroll
  for (int n2 = 0; n2 < 2; ++n2)
    wl[n2] = *(const f4*)(w + ((size_t)0 * BSZ + b0 + lr) * NX + (nt0 + n2) * 16 + g * 4);
  f4 z4 = {0.f, 0.f, 0.f, 0.f};
  for (int k = 0; k < KCH - 1; ++k) {
    const int p = k & 1;
    f4 wn[2] = {z4, z4};
    if (k < KCH - 2) {
#pragma unroll
      for (int n2 = 0; n2 < 2; ++n2)
        wn[n2] = *(const f4*)(w + ((size_t)(k + 1) * BSZ + b0 + lr) * NX + (nt0 + n2) * 16 + g * 4);
    }
    f4 acc[2] = {z4, z4};
#pragma unroll
    for (int kf = 0; kf < 8; ++kf) {
      acc[0] = mfma16(Ar[0][kf], af[kf], acc[0]);
      acc[1] = mfma16(Ar[1][kf], af[kf], acc[1]);
    }
#pragma unroll
    for (int n2 = 0; n2 < 2; ++n2) {
      acc[n2] += wl[n2];
      *(f4*)(xs + ((size_t)(k + 1) * BSZ + b0 + lr) * NX + (nt0 + n2) * 16 + g * 4) = acc[n2];
    }
    if (k < KCH - 2) {
#pragma unroll
      for (int n2 = 0; n2 < 2; ++n2)
        *(h4*)(xb + (p ^ 1) * 8192 + xwSwz(lr, (nt0 + n2) * 32 + g * 8)) = h4cvt(acc[n2]);
      LBAR();
#pragma unroll
      for (int kf = 0; kf < 8; ++kf)
        af[kf] = *(const h8*)(xb + (p ^ 1) * 8192 + xwSwz(lr, kf * 64 + g * 16));
    }
#pragma unroll
    for (int n2 = 0; n2 < 2; ++n2) wl[n2] = wn[n2];
  }
}

// ---------------- phase Y: true-init recurrence, emits exact y (LDS u path) ----------------
__global__ __launch_bounds__(512, 2) void k_recY(const float* __restrict__ u,
                                                 const _Float16* __restrict__ A16,
                                                 const _Float16* __restrict__ B16,
                                                 const _Float16* __restrict__ CA16,
                                                 const _Float16* __restrict__ CBD16,
                                                 const float* __restrict__ xs,
                                                 float* __restrict__ out) {
  __shared__ __align__(16) char sm[24576];
  char* xb = sm;
  char* ub = sm + 16384;
  const int tid = threadIdx.x, lane = tid & 63, wv = tid >> 6;
  const int g = lane >> 4, lr = lane & 15;
  const int chunk = blockIdx.x >> 3, btile = blockIdx.x & 7;
  const int b0 = btile * 16, t0 = chunk * LCH, nt0 = wv * 2;

  h8 Ar[2][8], Bf[2][4], Cf[8], Df[4];
#pragma unroll
  for (int n2 = 0; n2 < 2; ++n2) {
#pragma unroll
    for (int kf = 0; kf < 8; ++kf) {
      Ar[n2][kf] = *(const h8*)(A16 + (size_t)((nt0 + n2) * 16 + lr) * NX + kf * 32 + g * 8);
      PIN(Ar[n2][kf]);
    }
#pragma unroll
    for (int kf = 0; kf < 4; ++kf) {
      Bf[n2][kf] = *(const h8*)(B16 + (size_t)((nt0 + n2) * 16 + lr) * NU + kf * 32 + g * 8);
      PIN(Bf[n2][kf]);
    }
  }
#pragma unroll
  for (int kf = 0; kf < 8; ++kf) {
    Cf[kf] = *(const h8*)(CA16 + (size_t)(wv * 16 + lr) * NX + kf * 32 + g * 8);
    PIN(Cf[kf]);
  }
#pragma unroll
  for (int kf = 0; kf < 4; ++kf) {
    Df[kf] = *(const h8*)(CBD16 + (size_t)(wv * 16 + lr) * NU + kf * 32 + g * 8);
    PIN(Df[kf]);
  }
  h8 af[8];
#pragma unroll
  for (int kf = 0; kf < 8; ++kf) {
    const float* sp = xs + ((size_t)chunk * BSZ + b0 + lr) * NX + kf * 32 + g * 8;
    af[kf] = cvt8(*(const f4*)sp, *(const f4*)(sp + 4));
  }
  const int urow = tid >> 5, uuc = tid & 31;
  const float* ubase = u + (size_t)(b0 + urow) * (TT * NU) + uuc * 4;
  const int uoff = swz256(urow, uuc * 8);
  float* obase = out + (size_t)(b0 + lr) * (TT * NY) + wv * 16 + g * 4;
  {
    f4 r0 = *(const f4*)(ubase + (size_t)t0 * NU);
    *(h4*)(ub + uoff) = h4cvt(r0);
  }
  f4 urA = *(const f4*)(ubase + (size_t)(t0 + 1) * NU);
  f4 urB = *(const f4*)(ubase + (size_t)(t0 + 2 < TT ? t0 + 2 : TT - 1) * NU);
  __syncthreads();

  f4 z4 = {0.f, 0.f, 0.f, 0.f};
#pragma unroll 2
  for (int i = 0; i < LCH; ++i) {
    const int p = i & 1;
    if (i < LCH - 1) {
      int nt = t0 + i + 3;
      if (nt > TT - 1) nt = TT - 1;
      if (p == 0) {
        *(h4*)(ub + 4096 + uoff) = h4cvt(urA);
        urA = *(const f4*)(ubase + (size_t)nt * NU);
      } else {
        *(h4*)(ub + uoff) = h4cvt(urB);
        urB = *(const f4*)(ubase + (size_t)nt * NU);
      }
    }
    h8 uf[4];
#pragma unroll
    for (int kf = 0; kf < 4; ++kf)
      uf[kf] = *(const h8*)(ub + p * 4096 + swz256(lr, kf * 64 + g * 16));
    // x-update first (shortens pre-barrier critical path)
    if (i < LCH - 1) {
      __builtin_amdgcn_s_setprio(1);
      f4 xacc[2] = {z4, z4};
#pragma unroll
      for (int kf = 0; kf < 8; ++kf) {
        xacc[0] = mfma16(Ar[0][kf], af[kf], xacc[0]);
        xacc[1] = mfma16(Ar[1][kf], af[kf], xacc[1]);
      }
#pragma unroll
      for (int kf = 0; kf < 4; ++kf) {
        xacc[0] = mfma16(Bf[0][kf], uf[kf], xacc[0]);
        xacc[1] = mfma16(Bf[1][kf], uf[kf], xacc[1]);
      }
      __builtin_amdgcn_s_setprio(0);
#pragma unroll
      for (int n2 = 0; n2 < 2; ++n2)
        *(h4*)(xb + (p ^ 1) * 8192 + xwSwz(lr, (nt0 + n2) * 32 + g * 8)) = h4cvt(xacc[n2]);
    }
    __builtin_amdgcn_s_setprio(1);
    f4 yacc = z4;
#pragma unroll
    for (int kf = 0; kf < 8; ++kf) yacc = mfma16(Cf[kf], af[kf], yacc);
#pragma unroll
    for (int kf = 0; kf < 4; ++kf) yacc = mfma16(Df[kf], uf[kf], yacc);
    __builtin_amdgcn_s_setprio(0);
    int t = t0 + i + 1;
    if (t < TT) *(f4*)(obase + (size_t)t * NY) = yacc;
    if (i < LCH - 1) {
      LBAR();
#pragma unroll
      for (int kf = 0; kf < 8; ++kf)
        af[kf] = *(const h8*)(xb + (p ^ 1) * 8192 + xwSwz(lr, kf * 64 + g * 16));
    }
  }
}

extern "C" void kernel_launch(void* const* d_in, const int* in_sizes, int n_in,
                              void* d_out, int out_size, void* d_ws, size_t ws_size,
                              hipStream_t stream) {
  const float* u  = (const float*)d_in[0];
  const float* M  = (const float*)d_in[1];
  const float* B  = (const float*)d_in[2];
  const float* C  = (const float*)d_in[3];
  const float* D  = (const float*)d_in[4];
  const float* x0 = (const float*)d_in[5];
  float* out = (float*)d_out;
  char* ws = (char*)d_ws;

  float* E    = (float*)(ws + 0L);
  float* F    = (float*)(ws + 256L * 1024);
  float* X1   = (float*)(ws + 512L * 1024);
  float* Y1   = (float*)(ws + 768L * 1024);
  float* X2   = (float*)(ws + 1024L * 1024);
  float* Y2   = (float*)(ws + 1280L * 1024);
  float* Amat = (float*)(ws + 1536L * 1024);
  float* P2   = (float*)(ws + 1792L * 1024);
  float* P4   = (float*)(ws + 2048L * 1024);
  float* P8   = (float*)(ws + 2304L * 1024);
  float* P16  = (float*)(ws + 2560L * 1024);
  _Float16* A16   = (_Float16*)(ws + 2816L * 1024);
  _Float16* Ah16  = (_Float16*)(ws + 2944L * 1024);
  _Float16* B16   = (_Float16*)(ws + 3072L * 1024);
  _Float16* CA16  = (_Float16*)(ws + 3136L * 1024);
  _Float16* CBD16 = (_Float16*)(ws + 3200L * 1024);
  float* wbuf = (float*)(ws + 9408L * 1024);           // 8 MB
  float* xs   = (float*)(ws + 17600L * 1024);          // 8 MB

  MMJob nil = {nullptr, nullptr, nullptr, nullptr, nullptr, 0, 0, 0, 0};

  k_ef<<<224, 256, 0, stream>>>(M, B, C, D, x0, u, E, F, B16, out);
  k_ns0<<<128, 256, 0, stream>>>(E, X1, Y1);
  float *Xc = X1, *Yc = Y1, *Xn = X2, *Yn = Y2;
  for (int it = 0; it < 6; ++it) {
    MMJob jx = {Xc, Yc, nullptr, Xn, nullptr, 256, 256, 1, 0};
    MMJob jy = {Yc, Yc, nullptr, Yn, nullptr, 256, 256, 1, 64};
    k_mm<<<128, 256, 0, stream>>>(jx, jy, nil, 2);
    float* t1 = Xc; Xc = Xn; Xn = t1;
    float* t2 = Yc; Yc = Yn; Yn = t2;
  }
  {  // A = E^-1 F
    MMJob ja = {Xc, F, nullptr, Amat, A16, 256, 256, 0, 0};
    k_mm<<<64, 256, 0, stream>>>(ja, nil, nil, 1);
  }
  {  // A^2 ; CA -> CA16 ; CBD = C B + D -> CBD16
    MMJob j0 = {Amat, Amat, nullptr, P2, nullptr, 256, 256, 0, 0};
    MMJob j1 = {C, Amat, nullptr, nullptr, CA16, 128, 256, 0, 64};
    MMJob j2 = {C, B, D, nullptr, CBD16, 128, 128, 0, 96};
    k_mm<<<112, 256, 0, stream>>>(j0, j1, j2, 3);
  }
  {  // A^4
    MMJob j0 = {P2, P2, nullptr, P4, nullptr, 256, 256, 0, 0};
    k_mm<<<64, 256, 0, stream>>>(j0, nil, nil, 1);
  }
  {  // A^8
    MMJob j0 = {P4, P4, nullptr, P8, nullptr, 256, 256, 0, 0};
    k_mm<<<64, 256, 0, stream>>>(j0, nil, nil, 1);
  }
  {  // A^16
    MMJob j0 = {P8, P8, nullptr, P16, nullptr, 256, 256, 0, 0};
    k_mm<<<64, 256, 0, stream>>>(j0, nil, nil, 1);
  }
  {  // A^32 -> Ah16
    MMJob j0 = {P16, P16, nullptr, nullptr, Ah16, 256, 256, 0, 0};
    k_mm<<<64, 256, 0, stream>>>(j0, nil, nil, 1);
  }

  k_recW<<<512, 512, 0, stream>>>(u, A16, B16, wbuf);
  k_phB<<<8, 512, 0, stream>>>(x0, wbuf, Ah16, xs);
  k_recY<<<512, 512, 0, stream>>>(u, A16, B16, CA16, CBD16, xs, out);
}

// Round 17
// 339.528 us; speedup vs baseline: 1.2336x; 1.0235x over previous
//
#include <hip/hip_runtime.h>

#define NX 256
#define NU 128
#define NY 128
#define BSZ 128
#define TT 2048
#define LCH 32
#define KCH 64

typedef _Float16 h8 __attribute__((ext_vector_type(8)));
typedef _Float16 h4 __attribute__((ext_vector_type(4)));
typedef float f4 __attribute__((ext_vector_type(4)));

__device__ __forceinline__ f4 mfma16(h8 a, h8 b, f4 c) {
  return __builtin_amdgcn_mfma_f32_16x16x32_f16(a, b, c, 0, 0, 0);
}
#define PIN(x) asm volatile("" : "+v"(x))
#define LBAR() asm volatile("s_waitcnt lgkmcnt(0)\n\ts_barrier" ::: "memory")

__device__ __forceinline__ int swz256(int row, int bc) { return row * 256 + (bc ^ ((row & 7) << 4)); }
__device__ __forceinline__ int xwSwz(int row, int canon) {
  return row * 512 + (canon ^ ((row & 7) << 4) ^ ((canon & 16) << 1));
}

__device__ __forceinline__ h8 cvt8(f4 lo, f4 hi) {
  h8 h;
#pragma unroll
  for (int j = 0; j < 4; ++j) { h[j] = (_Float16)lo[j]; h[j + 4] = (_Float16)hi[j]; }
  return h;
}
__device__ __forceinline__ h4 h4cvt(f4 v) {
  h4 h;
#pragma unroll
  for (int j = 0; j < 4; ++j) h[j] = (_Float16)v[j];
  return h;
}
__device__ __forceinline__ h8 h8zero() {
  h8 h;
#pragma unroll
  for (int j = 0; j < 8; ++j) h[j] = (_Float16)0.0f;
  return h;
}

// ---- fp32 GEMM core: 32x32 tile, K=256, lda=256, dbuf K=64 rounds + reg prefetch ----
__device__ __forceinline__ void mm_core(const float* __restrict__ a, const float* __restrict__ b,
                                        int Nb, int i0, int j0, int tid,
                                        float (*As)[32][65], float (*Bs)[64][33],
                                        float acc[2][2]) {
  const int ar = tid >> 4, ac = (tid & 15) * 4;
  const int br = tid >> 3, bc = (tid & 7) * 4;
  const int tx = tid & 15, ty = tid >> 4;
  f4 pa0 = *(const f4*)(a + (size_t)(i0 + ar) * 256 + ac);
  f4 pa1 = *(const f4*)(a + (size_t)(i0 + ar + 16) * 256 + ac);
  f4 pb0 = *(const f4*)(b + (size_t)br * Nb + j0 + bc);
  f4 pb1 = *(const f4*)(b + (size_t)(br + 32) * Nb + j0 + bc);
  for (int r4 = 0; r4 < 4; ++r4) {
    const int bs = r4 & 1;
#pragma unroll
    for (int m = 0; m < 4; ++m) {
      As[bs][ar][ac + m] = pa0[m];
      As[bs][ar + 16][ac + m] = pa1[m];
      Bs[bs][br][bc + m] = pb0[m];
      Bs[bs][br + 32][bc + m] = pb1[m];
    }
    if (r4 < 3) {
      int kk = (r4 + 1) * 64;
      pa0 = *(const f4*)(a + (size_t)(i0 + ar) * 256 + kk + ac);
      pa1 = *(const f4*)(a + (size_t)(i0 + ar + 16) * 256 + kk + ac);
      pb0 = *(const f4*)(b + (size_t)(kk + br) * Nb + j0 + bc);
      pb1 = *(const f4*)(b + (size_t)(kk + br + 32) * Nb + j0 + bc);
    }
    __syncthreads();
#pragma unroll 8
    for (int k = 0; k < 64; ++k) {
      float a0 = As[bs][ty * 2][k], a1 = As[bs][ty * 2 + 1][k];
      float b0 = Bs[bs][k][tx * 2], b1 = Bs[bs][k][tx * 2 + 1];
      acc[0][0] += a0 * b0; acc[0][1] += a0 * b1;
      acc[1][0] += a1 * b0; acc[1][1] += a1 * b1;
    }
  }
}

// ---------------- E,F from M; y0 exact fp32; B16 cast ----------------
__global__ __launch_bounds__(256) void k_ef(const float* __restrict__ M, const float* __restrict__ B,
                                            const float* __restrict__ C, const float* __restrict__ D,
                                            const float* __restrict__ x0, const float* __restrict__ u,
                                            float* __restrict__ E, float* __restrict__ F,
                                            _Float16* __restrict__ B16, float* __restrict__ out) {
  const int tid = threadIdx.x;
  int z = blockIdx.x >> 6;
  if (z >= 2) {
    if (blockIdx.x < 192) {  // y0
      int idx = (blockIdx.x - 128) * 256 + tid;
      int b = idx >> 7, col = idx & 127;
      const float* crow = C + (size_t)col * 256;
      const float* drow = D + (size_t)col * 128;
      const float* ur = u + (size_t)b * (TT * NU);
      float s = 0.f;
#pragma unroll 8
      for (int j = 0; j < 256; j += 4) {
        f4 cv = *(const f4*)(crow + j);
        f4 xv = *(const f4*)(x0 + j);
        s += cv[0] * xv[0] + cv[1] * xv[1] + cv[2] * xv[2] + cv[3] * xv[3];
      }
#pragma unroll 8
      for (int j = 0; j < 128; j += 4) {
        f4 dv = *(const f4*)(drow + j);
        f4 uv = *(const f4*)(ur + j);
        s += dv[0] * uv[0] + dv[1] * uv[1] + dv[2] * uv[2] + dv[3] * uv[3];
      }
      out[(size_t)b * (TT * NY) + col] = s;
    } else {  // B16 cast
      int i = (blockIdx.x - 192) * 1024 + tid;
      B16[i] = (_Float16)B[i];
      B16[i + 256] = (_Float16)B[i + 256];
      B16[i + 512] = (_Float16)B[i + 512];
      B16[i + 768] = (_Float16)B[i + 768];
    }
    return;
  }
  __shared__ float Ps[2][32][65], Qs[2][32][65];
  int tile = blockIdx.x & 63;
  int i0 = (tile >> 3) * 32, j0 = (tile & 7) * 32;
  const int ar = tid >> 4, ac = (tid & 15) * 4;
  const int tx = tid & 15, ty = tid >> 4;
  float acc[2][2] = {{0.f, 0.f}, {0.f, 0.f}};
  int np = (z == 0) ? 2 : 1;
  int rc = 0;
  for (int p = 0; p < np; ++p) {
    int po = (z == 0) ? p * 256 : 256;
    int qo = (z == 0) ? p * 256 : 0;
    f4 p0 = *(const f4*)(M + (size_t)(i0 + po + ar) * 512 + ac);
    f4 p1 = *(const f4*)(M + (size_t)(i0 + po + ar + 16) * 512 + ac);
    f4 q0 = *(const f4*)(M + (size_t)(j0 + qo + ar) * 512 + ac);
    f4 q1 = *(const f4*)(M + (size_t)(j0 + qo + ar + 16) * 512 + ac);
    for (int kk = 0; kk < 512; kk += 64) {
      const int bs = rc & 1;
      ++rc;
#pragma unroll
      for (int m = 0; m < 4; ++m) {
        Ps[bs][ar][ac + m] = p0[m];
        Ps[bs][ar + 16][ac + m] = p1[m];
        Qs[bs][ar][ac + m] = q0[m];
        Qs[bs][ar + 16][ac + m] = q1[m];
      }
      if (kk < 448) {
        int k2 = kk + 64;
        p0 = *(const f4*)(M + (size_t)(i0 + po + ar) * 512 + k2 + ac);
        p1 = *(const f4*)(M + (size_t)(i0 + po + ar + 16) * 512 + k2 + ac);
        q0 = *(const f4*)(M + (size_t)(j0 + qo + ar) * 512 + k2 + ac);
        q1 = *(const f4*)(M + (size_t)(j0 + qo + ar + 16) * 512 + k2 + ac);
      }
      __syncthreads();
#pragma unroll 8
      for (int k = 0; k < 64; ++k) {
        float a0 = Ps[bs][ty * 2][k], a1 = Ps[bs][ty * 2 + 1][k];
        float b0 = Qs[bs][tx * 2][k], b1 = Qs[bs][tx * 2 + 1][k];
        acc[0][0] += a0 * b0; acc[0][1] += a0 * b1;
        acc[1][0] += a1 * b0; acc[1][1] += a1 * b1;
      }
    }
  }
#pragma unroll
  for (int ii = 0; ii < 2; ++ii)
#pragma unroll
    for (int jj = 0; jj < 2; ++jj) {
      int i = i0 + ty * 2 + ii, j = j0 + tx * 2 + jj;
      if (z == 0) {
        float v = 0.5f * acc[ii][jj];
        if (i == j) v += 1e-9f;
        E[i * 256 + j] = v;
      } else {
        F[i * 256 + j] = acc[ii][jj];
      }
    }
}

// ---------------- NS init ----------------
__global__ __launch_bounds__(256) void k_ns0(const float* __restrict__ E,
                                             float* __restrict__ X, float* __restrict__ Y) {
  __shared__ float As[2][32][65];
  __shared__ float Bs[2][64][33];
  __shared__ float s1[256], red[256];
  const int tid = threadIdx.x;
  {
    float s = 0.f;
    const float* row = E + (size_t)tid * 256;
#pragma unroll 8
    for (int j = 0; j < 256; j += 4) {
      f4 e = *(const f4*)(row + j);
      s += e[0] + e[1] + e[2] + e[3];
    }
    s1[tid] = s; red[tid] = s * s;
  }
  __syncthreads();
  for (int o = 128; o > 0; o >>= 1) { if (tid < o) red[tid] += red[tid + o]; __syncthreads(); }
  float n1 = red[0];
  __syncthreads();
  {
    float s = 0.f;
    const float* row = E + (size_t)tid * 256;
#pragma unroll 8
    for (int j = 0; j < 256; j += 4) {
      f4 e = *(const f4*)(row + j);
      f4 vv = *(const f4*)(&s1[j]);
      s += e[0] * vv[0] + e[1] * vv[1] + e[2] * vv[2] + e[3] * vv[3];
    }
    red[tid] = s * s;
  }
  __syncthreads();
  for (int o = 128; o > 0; o >>= 1) { if (tid < o) red[tid] += red[tid + o]; __syncthreads(); }
  float c = sqrtf(n1 / red[0]);
  __syncthreads();
  if (blockIdx.x < 64) {
    int i0 = (blockIdx.x >> 3) * 32, j0 = (blockIdx.x & 7) * 32;
    float acc[2][2] = {{0.f, 0.f}, {0.f, 0.f}};
    mm_core(E, E, 256, i0, j0, tid, As, Bs, acc);
    int tx = tid & 15, ty = tid >> 4;
#pragma unroll
    for (int ii = 0; ii < 2; ++ii)
#pragma unroll
      for (int jj = 0; jj < 2; ++jj) {
        int i = i0 + ty * 2 + ii, j = j0 + tx * 2 + jj;
        Y[(size_t)i * 256 + j] = 2.f * c * E[(size_t)i * 256 + j] - c * c * acc[ii][jj];
      }
  } else {
    int idx = (blockIdx.x - 64) * 1024 + tid * 4;
    int i = idx >> 8, j = idx & 255;
    f4 e = *(const f4*)(E + idx);
    f4 v;
#pragma unroll
    for (int m = 0; m < 4; ++m) v[m] = ((j + m) == i ? 2.f * c : 0.f) - c * c * e[m];
    *(f4*)(X + idx) = v;
  }
}

// ---------------- multi-job fp32 GEMM ----------------
struct MMJob {
  const float* a; const float* b; const float* add;
  float* d32; _Float16* d16;
  int M, N, mode, blk0;
};

__global__ __launch_bounds__(256) void k_mm(MMJob j0, MMJob j1, MMJob j2, int njobs) {
  __shared__ float As[2][32][65];
  __shared__ float Bs[2][64][33];
  const int tid = threadIdx.x;
  int bid = blockIdx.x;
  MMJob jb = j0;
  if (njobs > 1 && bid >= j1.blk0) jb = j1;
  if (njobs > 2 && bid >= j2.blk0) jb = j2;
  int rel = bid - jb.blk0;
  int ntile = jb.N >> 5;
  int i0 = (rel / ntile) * 32, j0g = (rel % ntile) * 32;
  float acc[2][2] = {{0.f, 0.f}, {0.f, 0.f}};
  mm_core(jb.a, jb.b, jb.N, i0, j0g, tid, As, Bs, acc);
  int tx = tid & 15, ty = tid >> 4;
#pragma unroll
  for (int ii = 0; ii < 2; ++ii)
#pragma unroll
    for (int jj = 0; jj < 2; ++jj) {
      int i = i0 + ty * 2 + ii, j = j0g + tx * 2 + jj;
      size_t o = (size_t)i * jb.N + j;
      float v = acc[ii][jj];
      if (jb.mode == 1) v = 2.f * jb.a[(size_t)i * 256 + j] - v;
      else if (jb.add) v += jb.add[o];
      if (jb.d32) jb.d32[o] = v;
      if (jb.d16) jb.d16[o] = (_Float16)v;
    }
}

// ---------------- phase W: zero-init chunk increments, PAIR-STEP (16 barriers) ----------------
// x_{t+2} = A^2 x_t + (A B) u_t + B u_{t+1}
__global__ __launch_bounds__(512, 2) void k_recW(const float* __restrict__ u,
                                                 const _Float16* __restrict__ A216,
                                                 const _Float16* __restrict__ AB16,
                                                 const _Float16* __restrict__ B16,
                                                 float* __restrict__ w) {
  __shared__ __align__(16) char sm[32768];
  char* xb = sm;          // 2 x [16][256] h16
  char* ub = sm + 16384;  // 4 slots x [16][128] h16
  const int tid = threadIdx.x, lane = tid & 63, wv = tid >> 6;
  const int g = lane >> 4, lr = lane & 15;
  const int chunk = blockIdx.x >> 3, btile = blockIdx.x & 7;
  const int b0 = btile * 16, t0 = chunk * LCH, nt0 = wv * 2;

  h8 A2f[2][8], ABf[2][4], Bf[2][4];
#pragma unroll
  for (int n2 = 0; n2 < 2; ++n2) {
#pragma unroll
    for (int kf = 0; kf < 8; ++kf) {
      A2f[n2][kf] = *(const h8*)(A216 + (size_t)((nt0 + n2) * 16 + lr) * NX + kf * 32 + g * 8);
      PIN(A2f[n2][kf]);
    }
#pragma unroll
    for (int kf = 0; kf < 4; ++kf) {
      ABf[n2][kf] = *(const h8*)(AB16 + (size_t)((nt0 + n2) * 16 + lr) * NU + kf * 32 + g * 8);
      PIN(ABf[n2][kf]);
      Bf[n2][kf] = *(const h8*)(B16 + (size_t)((nt0 + n2) * 16 + lr) * NU + kf * 32 + g * 8);
      PIN(Bf[n2][kf]);
    }
  }
  const int urow = tid >> 5, uuc = tid & 31;
  const float* ubase = u + (size_t)(b0 + urow) * (TT * NU) + uuc * 4;
  const int uoff = swz256(urow, uuc * 8);
  {
    f4 r0 = *(const f4*)(ubase + (size_t)t0 * NU);
    *(h4*)(ub + uoff) = h4cvt(r0);
    f4 r1 = *(const f4*)(ubase + (size_t)(t0 + 1) * NU);
    *(h4*)(ub + 4096 + uoff) = h4cvt(r1);
  }
  f4 urA = *(const f4*)(ubase + (size_t)(t0 + 2) * NU);
  f4 urB = *(const f4*)(ubase + (size_t)(t0 + 3) * NU);
  h8 af[8];
#pragma unroll
  for (int kf = 0; kf < 8; ++kf) af[kf] = h8zero();
  __syncthreads();

  f4 z4 = {0.f, 0.f, 0.f, 0.f};
  f4 xacc[2];
#pragma unroll 2
  for (int p = 0; p < 16; ++p) {
    const int q = p & 1;
    const int s0 = (2 * p) & 3, s1 = (2 * p + 1) & 3;
    if (p < 15) {
      *(h4*)(ub + ((2 * p + 2) & 3) * 4096 + uoff) = h4cvt(urA);
      *(h4*)(ub + ((2 * p + 3) & 3) * 4096 + uoff) = h4cvt(urB);
      int na = t0 + 2 * p + 4, nb = t0 + 2 * p + 5;
      if (na > TT - 1) na = TT - 1;
      if (nb > TT - 1) nb = TT - 1;
      urA = *(const f4*)(ubase + (size_t)na * NU);
      urB = *(const f4*)(ubase + (size_t)nb * NU);
    }
    h8 ufa[4], ufb[4];
#pragma unroll
    for (int kf = 0; kf < 4; ++kf) {
      ufa[kf] = *(const h8*)(ub + s0 * 4096 + swz256(lr, kf * 64 + g * 16));
      ufb[kf] = *(const h8*)(ub + s1 * 4096 + swz256(lr, kf * 64 + g * 16));
    }
    __builtin_amdgcn_s_setprio(1);
    xacc[0] = z4; xacc[1] = z4;
#pragma unroll
    for (int kf = 0; kf < 8; ++kf) {
      xacc[0] = mfma16(A2f[0][kf], af[kf], xacc[0]);
      xacc[1] = mfma16(A2f[1][kf], af[kf], xacc[1]);
    }
#pragma unroll
    for (int kf = 0; kf < 4; ++kf) {
      xacc[0] = mfma16(ABf[0][kf], ufa[kf], xacc[0]);
      xacc[1] = mfma16(ABf[1][kf], ufa[kf], xacc[1]);
    }
#pragma unroll
    for (int kf = 0; kf < 4; ++kf) {
      xacc[0] = mfma16(Bf[0][kf], ufb[kf], xacc[0]);
      xacc[1] = mfma16(Bf[1][kf], ufb[kf], xacc[1]);
    }
    __builtin_amdgcn_s_setprio(0);
    if (p < 15) {
#pragma unroll
      for (int n2 = 0; n2 < 2; ++n2)
        *(h4*)(xb + (q ^ 1) * 8192 + xwSwz(lr, (nt0 + n2) * 32 + g * 8)) = h4cvt(xacc[n2]);
      LBAR();
#pragma unroll
      for (int kf = 0; kf < 8; ++kf)
        af[kf] = *(const h8*)(xb + (q ^ 1) * 8192 + xwSwz(lr, kf * 64 + g * 16));
    }
  }
#pragma unroll
  for (int n2 = 0; n2 < 2; ++n2)
    *(f4*)(w + ((size_t)chunk * BSZ + b0 + lr) * NX + (nt0 + n2) * 16 + g * 4) = xacc[n2];
}

// ---------------- phase B: sequential chunk combine ----------------
__global__ __launch_bounds__(512, 2) void k_phB(const float* __restrict__ x0,
                                                const float* __restrict__ w,
                                                const _Float16* __restrict__ Ah16,
                                                float* __restrict__ xs) {
  __shared__ __align__(16) char xb[16384];
  const int tid = threadIdx.x, lane = tid & 63, wv = tid >> 6;
  const int g = lane >> 4, lr = lane & 15;
  const int b0 = blockIdx.x * 16, nt0 = wv * 2;
  h8 Ar[2][8];
#pragma unroll
  for (int n2 = 0; n2 < 2; ++n2)
#pragma unroll
    for (int kf = 0; kf < 8; ++kf) {
      Ar[n2][kf] = *(const h8*)(Ah16 + (size_t)((nt0 + n2) * 16 + lr) * NX + kf * 32 + g * 8);
      PIN(Ar[n2][kf]);
    }
  for (int s = 0; s < 8; ++s) {
    int e = tid + s * 512;
    int row = e >> 8, c = e & 255;
    xs[(size_t)(b0 + row) * NX + c] = x0[c];
  }
  h8 af[8];
#pragma unroll
  for (int kf = 0; kf < 8; ++kf) {
    const float* sp = x0 + kf * 32 + g * 8;
    af[kf] = cvt8(*(const f4*)sp, *(const f4*)(sp + 4));
  }
  f4 wl[2];
#pragma unroll
  for (int n2 = 0; n2 < 2; ++n2)
    wl[n2] = *(const f4*)(w + ((size_t)0 * BSZ + b0 + lr) * NX + (nt0 + n2) * 16 + g * 4);
  f4 z4 = {0.f, 0.f, 0.f, 0.f};
  for (int k = 0; k < KCH - 1; ++k) {
    const int p = k & 1;
    f4 wn[2] = {z4, z4};
    if (k < KCH - 2) {
#pragma unroll
      for (int n2 = 0; n2 < 2; ++n2)
        wn[n2] = *(const f4*)(w + ((size_t)(k + 1) * BSZ + b0 + lr) * NX + (nt0 + n2) * 16 + g * 4);
    }
    f4 acc[2] = {z4, z4};
#pragma unroll
    for (int kf = 0; kf < 8; ++kf) {
      acc[0] = mfma16(Ar[0][kf], af[kf], acc[0]);
      acc[1] = mfma16(Ar[1][kf], af[kf], acc[1]);
    }
#pragma unroll
    for (int n2 = 0; n2 < 2; ++n2) {
      acc[n2] += wl[n2];
      *(f4*)(xs + ((size_t)(k + 1) * BSZ + b0 + lr) * NX + (nt0 + n2) * 16 + g * 4) = acc[n2];
    }
    if (k < KCH - 2) {
#pragma unroll
      for (int n2 = 0; n2 < 2; ++n2)
        *(h4*)(xb + (p ^ 1) * 8192 + xwSwz(lr, (nt0 + n2) * 32 + g * 8)) = h4cvt(acc[n2]);
      LBAR();
#pragma unroll
      for (int kf = 0; kf < 8; ++kf)
        af[kf] = *(const h8*)(xb + (p ^ 1) * 8192 + xwSwz(lr, kf * 64 + g * 16));
    }
#pragma unroll
    for (int n2 = 0; n2 < 2; ++n2) wl[n2] = wn[n2];
  }
}

// ---------------- phase Y: true-init recurrence, emits exact y (LDS u path) ----------------
__global__ __launch_bounds__(512, 2) void k_recY(const float* __restrict__ u,
                                                 const _Float16* __restrict__ A16,
                                                 const _Float16* __restrict__ B16,
                                                 const _Float16* __restrict__ CA16,
                                                 const _Float16* __restrict__ CBD16,
                                                 const float* __restrict__ xs,
                                                 float* __restrict__ out) {
  __shared__ __align__(16) char sm[24576];
  char* xb = sm;
  char* ub = sm + 16384;
  const int tid = threadIdx.x, lane = tid & 63, wv = tid >> 6;
  const int g = lane >> 4, lr = lane & 15;
  const int chunk = blockIdx.x >> 3, btile = blockIdx.x & 7;
  const int b0 = btile * 16, t0 = chunk * LCH, nt0 = wv * 2;

  h8 Ar[2][8], Bf[2][4], Cf[8], Df[4];
#pragma unroll
  for (int n2 = 0; n2 < 2; ++n2) {
#pragma unroll
    for (int kf = 0; kf < 8; ++kf) {
      Ar[n2][kf] = *(const h8*)(A16 + (size_t)((nt0 + n2) * 16 + lr) * NX + kf * 32 + g * 8);
      PIN(Ar[n2][kf]);
    }
#pragma unroll
    for (int kf = 0; kf < 4; ++kf) {
      Bf[n2][kf] = *(const h8*)(B16 + (size_t)((nt0 + n2) * 16 + lr) * NU + kf * 32 + g * 8);
      PIN(Bf[n2][kf]);
    }
  }
#pragma unroll
  for (int kf = 0; kf < 8; ++kf) {
    Cf[kf] = *(const h8*)(CA16 + (size_t)(wv * 16 + lr) * NX + kf * 32 + g * 8);
    PIN(Cf[kf]);
  }
#pragma unroll
  for (int kf = 0; kf < 4; ++kf) {
    Df[kf] = *(const h8*)(CBD16 + (size_t)(wv * 16 + lr) * NU + kf * 32 + g * 8);
    PIN(Df[kf]);
  }
  h8 af[8];
#pragma unroll
  for (int kf = 0; kf < 8; ++kf) {
    const float* sp = xs + ((size_t)chunk * BSZ + b0 + lr) * NX + kf * 32 + g * 8;
    af[kf] = cvt8(*(const f4*)sp, *(const f4*)(sp + 4));
  }
  const int urow = tid >> 5, uuc = tid & 31;
  const float* ubase = u + (size_t)(b0 + urow) * (TT * NU) + uuc * 4;
  const int uoff = swz256(urow, uuc * 8);
  float* obase = out + (size_t)(b0 + lr) * (TT * NY) + wv * 16 + g * 4;
  {
    f4 r0 = *(const f4*)(ubase + (size_t)t0 * NU);
    *(h4*)(ub + uoff) = h4cvt(r0);
  }
  f4 urA = *(const f4*)(ubase + (size_t)(t0 + 1) * NU);
  f4 urB = *(const f4*)(ubase + (size_t)(t0 + 2 < TT ? t0 + 2 : TT - 1) * NU);
  __syncthreads();

  f4 z4 = {0.f, 0.f, 0.f, 0.f};
#pragma unroll 2
  for (int i = 0; i < LCH; ++i) {
    const int p = i & 1;
    if (i < LCH - 1) {
      int nt = t0 + i + 3;
      if (nt > TT - 1) nt = TT - 1;
      if (p == 0) {
        *(h4*)(ub + 4096 + uoff) = h4cvt(urA);
        urA = *(const f4*)(ubase + (size_t)nt * NU);
      } else {
        *(h4*)(ub + uoff) = h4cvt(urB);
        urB = *(const f4*)(ubase + (size_t)nt * NU);
      }
    }
    h8 uf[4];
#pragma unroll
    for (int kf = 0; kf < 4; ++kf)
      uf[kf] = *(const h8*)(ub + p * 4096 + swz256(lr, kf * 64 + g * 16));
    // x-update first (shortens pre-barrier critical path)
    if (i < LCH - 1) {
      __builtin_amdgcn_s_setprio(1);
      f4 xacc[2] = {z4, z4};
#pragma unroll
      for (int kf = 0; kf < 8; ++kf) {
        xacc[0] = mfma16(Ar[0][kf], af[kf], xacc[0]);
        xacc[1] = mfma16(Ar[1][kf], af[kf], xacc[1]);
      }
#pragma unroll
      for (int kf = 0; kf < 4; ++kf) {
        xacc[0] = mfma16(Bf[0][kf], uf[kf], xacc[0]);
        xacc[1] = mfma16(Bf[1][kf], uf[kf], xacc[1]);
      }
      __builtin_amdgcn_s_setprio(0);
#pragma unroll
      for (int n2 = 0; n2 < 2; ++n2)
        *(h4*)(xb + (p ^ 1) * 8192 + xwSwz(lr, (nt0 + n2) * 32 + g * 8)) = h4cvt(xacc[n2]);
    }
    __builtin_amdgcn_s_setprio(1);
    f4 yacc = z4;
#pragma unroll
    for (int kf = 0; kf < 8; ++kf) yacc = mfma16(Cf[kf], af[kf], yacc);
#pragma unroll
    for (int kf = 0; kf < 4; ++kf) yacc = mfma16(Df[kf], uf[kf], yacc);
    __builtin_amdgcn_s_setprio(0);
    int t = t0 + i + 1;
    if (t < TT) *(f4*)(obase + (size_t)t * NY) = yacc;
    if (i < LCH - 1) {
      LBAR();
#pragma unroll
      for (int kf = 0; kf < 8; ++kf)
        af[kf] = *(const h8*)(xb + (p ^ 1) * 8192 + xwSwz(lr, kf * 64 + g * 16));
    }
  }
}

extern "C" void kernel_launch(void* const* d_in, const int* in_sizes, int n_in,
                              void* d_out, int out_size, void* d_ws, size_t ws_size,
                              hipStream_t stream) {
  const float* u  = (const float*)d_in[0];
  const float* M  = (const float*)d_in[1];
  const float* B  = (const float*)d_in[2];
  const float* C  = (const float*)d_in[3];
  const float* D  = (const float*)d_in[4];
  const float* x0 = (const float*)d_in[5];
  float* out = (float*)d_out;
  char* ws = (char*)d_ws;

  float* E    = (float*)(ws + 0L);
  float* F    = (float*)(ws + 256L * 1024);
  float* X1   = (float*)(ws + 512L * 1024);
  float* Y1   = (float*)(ws + 768L * 1024);
  float* X2   = (float*)(ws + 1024L * 1024);
  float* Y2   = (float*)(ws + 1280L * 1024);
  float* Amat = (float*)(ws + 1536L * 1024);
  float* P2   = (float*)(ws + 1792L * 1024);
  float* P4   = (float*)(ws + 2048L * 1024);
  float* P8   = (float*)(ws + 2304L * 1024);
  float* P16  = (float*)(ws + 2560L * 1024);
  _Float16* A16   = (_Float16*)(ws + 2816L * 1024);
  _Float16* Ah16  = (_Float16*)(ws + 2944L * 1024);
  _Float16* B16   = (_Float16*)(ws + 3072L * 1024);
  _Float16* CA16  = (_Float16*)(ws + 3136L * 1024);
  _Float16* CBD16 = (_Float16*)(ws + 3200L * 1024);
  _Float16* A216  = (_Float16*)(ws + 3264L * 1024);   // 128 KB
  _Float16* AB16  = (_Float16*)(ws + 3392L * 1024);   // 64 KB
  float* wbuf = (float*)(ws + 9408L * 1024);           // 8 MB
  float* xs   = (float*)(ws + 17600L * 1024);          // 8 MB

  MMJob nil = {nullptr, nullptr, nullptr, nullptr, nullptr, 0, 0, 0, 0};

  k_ef<<<224, 256, 0, stream>>>(M, B, C, D, x0, u, E, F, B16, out);
  k_ns0<<<128, 256, 0, stream>>>(E, X1, Y1);
  float *Xc = X1, *Yc = Y1, *Xn = X2, *Yn = Y2;
  for (int it = 0; it < 6; ++it) {
    MMJob jx = {Xc, Yc, nullptr, Xn, nullptr, 256, 256, 1, 0};
    MMJob jy = {Yc, Yc, nullptr, Yn, nullptr, 256, 256, 1, 64};
    k_mm<<<128, 256, 0, stream>>>(jx, jy, nil, 2);
    float* t1 = Xc; Xc = Xn; Xn = t1;
    float* t2 = Yc; Yc = Yn; Yn = t2;
  }
  {  // A = E^-1 F
    MMJob ja = {Xc, F, nullptr, Amat, A16, 256, 256, 0, 0};
    k_mm<<<64, 256, 0, stream>>>(ja, nil, nil, 1);
  }
  {  // A^2 (+A216 cast) ; CA -> CA16 ; CBD = C B + D -> CBD16
    MMJob j0 = {Amat, Amat, nullptr, P2, A216, 256, 256, 0, 0};
    MMJob j1 = {C, Amat, nullptr, nullptr, CA16, 128, 256, 0, 64};
    MMJob j2 = {C, B, D, nullptr, CBD16, 128, 128, 0, 96};
    k_mm<<<112, 256, 0, stream>>>(j0, j1, j2, 3);
  }
  {  // A^4 ; AB = A*B -> AB16
    MMJob j0 = {P2, P2, nullptr, P4, nullptr, 256, 256, 0, 0};
    MMJob j1 = {Amat, B, nullptr, nullptr, AB16, 256, 128, 0, 64};
    k_mm<<<96, 256, 0, stream>>>(j0, j1, nil, 2);
  }
  {  // A^8
    MMJob j0 = {P4, P4, nullptr, P8, nullptr, 256, 256, 0, 0};
    k_mm<<<64, 256, 0, stream>>>(j0, nil, nil, 1);
  }
  {  // A^16
    MMJob j0 = {P8, P8, nullptr, P16, nullptr, 256, 256, 0, 0};
    k_mm<<<64, 256, 0, stream>>>(j0, nil, nil, 1);
  }
  {  // A^32 -> Ah16
    MMJob j0 = {P16, P16, nullptr, nullptr, Ah16, 256, 256, 0, 0};
    k_mm<<<64, 256, 0, stream>>>(j0, nil, nil, 1);
  }

  k_recW<<<512, 512, 0, stream>>>(u, A216, AB16, B16, wbuf);
  k_phB<<<8, 512, 0, stream>>>(x0, wbuf, Ah16, xs);
  k_recY<<<512, 512, 0, stream>>>(u, A16, B16, CA16, CBD16, xs, out);
}